// Round 1
// baseline (1406.368 us; speedup 1.0000x reference)
//
#include <hip/hip_runtime.h>
#include <hip/hip_bf16.h>
#include <math.h>

#define NN 50000
#define EE 400000
#define ETOT (NN + EE)

// ---------- helpers ----------
__device__ __forceinline__ unsigned fkey(float f) {
    unsigned u = __float_as_uint(f);
    return (u & 0x80000000u) ? ~u : (u | 0x80000000u);
}
__device__ __forceinline__ float funkey(unsigned u) {
    return __uint_as_float((u & 0x80000000u) ? (u & 0x7fffffffu) : ~u);
}
__device__ __forceinline__ float gelu_f(float x) {
    return 0.5f * x * (1.f + erff(x * 0.7071067811865476f));
}
__device__ __forceinline__ float elu_f(float x) {
    return x > 0.f ? x : expm1f(x);
}

// ---------- ea mean (sum) ----------
__global__ __launch_bounds__(256) void k_ea_reduce(const float* __restrict__ ea,
                                                   float* __restrict__ ea_sum, int E) {
    float s[8];
#pragma unroll
    for (int i = 0; i < 8; i++) s[i] = 0.f;
    for (int e = blockIdx.x * blockDim.x + threadIdx.x; e < E; e += gridDim.x * blockDim.x) {
        const float4* p = (const float4*)(ea + (size_t)e * 8);
        float4 a = p[0], b = p[1];
        s[0] += a.x; s[1] += a.y; s[2] += a.z; s[3] += a.w;
        s[4] += b.x; s[5] += b.y; s[6] += b.z; s[7] += b.w;
    }
#pragma unroll
    for (int o = 32; o; o >>= 1)
#pragma unroll
        for (int i = 0; i < 8; i++) s[i] += __shfl_xor(s[i], o, 64);
    __shared__ float sh[4][8];
    int lane = threadIdx.x & 63, w = threadIdx.x >> 6;
    if (lane == 0)
#pragma unroll
        for (int i = 0; i < 8; i++) sh[w][i] = s[i];
    __syncthreads();
    if (threadIdx.x < 8) {
        float v = sh[0][threadIdx.x] + sh[1][threadIdx.x] + sh[2][threadIdx.x] + sh[3][threadIdx.x];
        atomicAdd(ea_sum + threadIdx.x, v);
    }
}

// ---------- node transform 1: xl1 = x@Wl1+bl1, xr1 = x@Wr1+br1 ----------
__global__ __launch_bounds__(256) void k_ntrans1(const float* __restrict__ x,
                                                 const float* __restrict__ Wl, const float* __restrict__ bl,
                                                 const float* __restrict__ Wr, const float* __restrict__ br,
                                                 float* __restrict__ xl1, float* __restrict__ xr1, int N) {
    __shared__ float swl[16 * 256];
    __shared__ float swr[16 * 256];
    __shared__ float sx[32 * 16];
    int t = threadIdx.x;
#pragma unroll
    for (int k = 0; k < 16; k++) { swl[k * 256 + t] = Wl[k * 256 + t]; swr[k * 256 + t] = Wr[k * 256 + t]; }
    int n0 = blockIdx.x * 32;
    for (int i = t; i < 32 * 16; i += 256) {
        int n = n0 + (i >> 4);
        sx[i] = (n < N) ? x[(size_t)n * 16 + (i & 15)] : 0.f;
    }
    __syncthreads();
    float bL = bl[t], bR = br[t];
    for (int ni = 0; ni < 32; ni++) {
        int n = n0 + ni;
        if (n >= N) break;
        float al = bL, ar = bR;
#pragma unroll
        for (int k = 0; k < 16; k++) {
            float xv = sx[ni * 16 + k];
            al += xv * swl[k * 256 + t];
            ar += xv * swr[k * 256 + t];
        }
        xl1[(size_t)n * 256 + t] = al;
        xr1[(size_t)n * 256 + t] = ar;
    }
}

// ---------- conv1 attention logits + segment max ----------
__global__ __launch_bounds__(256) void k_alpha1(const float* __restrict__ xl1, const float* __restrict__ xr1,
                                                const int* __restrict__ ei, const float* __restrict__ ea,
                                                const float* __restrict__ ea_sum, const float* __restrict__ We1,
                                                const float* __restrict__ att1,
                                                float* __restrict__ alpha_out, unsigned* __restrict__ amax,
                                                int E, int N) {
    __shared__ float swe[8 * 256];
    int t = threadIdx.x;
    for (int i = t; i < 8 * 256; i += 256) swe[i] = We1[i];
    __syncthreads();
    int lane = t & 63, w = t >> 6;
    int Etot = E + N;
    for (long long e = (long long)blockIdx.x * 4 + w; e < Etot; e += (long long)gridDim.x * 4) {
        int ie = (int)e;
        int s, d;
        float eav[8];
        if (ie < E) {
            s = ei[ie]; d = ei[E + ie];
#pragma unroll
            for (int k = 0; k < 8; k++) eav[k] = ea[(size_t)ie * 8 + k];
        } else {
            s = d = ie - E;
            float invE = 1.f / (float)E;
#pragma unroll
            for (int k = 0; k < 8; k++) eav[k] = ea_sum[k] * invE;
        }
        float p[4];
#pragma unroll
        for (int h = 0; h < 4; h++) {
            int c = h * 64 + lane;
            float v = xl1[(size_t)s * 256 + c] + xr1[(size_t)d * 256 + c];
#pragma unroll
            for (int k = 0; k < 8; k++) v += eav[k] * swe[k * 256 + c];
            v = v > 0.f ? v : 0.2f * v;
            p[h] = v * att1[c];
        }
#pragma unroll
        for (int o = 32; o; o >>= 1) {
            p[0] += __shfl_xor(p[0], o, 64);
            p[1] += __shfl_xor(p[1], o, 64);
            p[2] += __shfl_xor(p[2], o, 64);
            p[3] += __shfl_xor(p[3], o, 64);
        }
        if (lane < 4) {
            alpha_out[(size_t)ie * 4 + lane] = p[lane];
            atomicMax(amax + (size_t)d * 4 + lane, fkey(p[lane]));
        }
    }
}

// ---------- conv1 exp + denom ----------
__global__ __launch_bounds__(256) void k_exp1(float* __restrict__ alpha, const int* __restrict__ ei,
                                              const unsigned* __restrict__ amax, float* __restrict__ denom,
                                              int E, int N) {
    int i = blockIdx.x * blockDim.x + threadIdx.x;
    int tot = (E + N) * 4;
    if (i >= tot) return;
    int e = i >> 2, h = i & 3;
    int d = (e < E) ? ei[E + e] : (e - E);
    float m = funkey(amax[(size_t)d * 4 + h]);
    float v = expf(alpha[i] - m);
    alpha[i] = v;
    atomicAdd(denom + (size_t)d * 4 + h, v);
}

// ---------- conv1 aggregation: out1[d] += xl1[s] * expa ----------
__global__ __launch_bounds__(256) void k_agg1(const float* __restrict__ xl1, const float* __restrict__ expa,
                                              const int* __restrict__ ei, float* __restrict__ out,
                                              int E, int N) {
    int t = threadIdx.x, lane = t & 63, w = t >> 6;
    int Etot = E + N;
    for (long long e = (long long)blockIdx.x * 4 + w; e < Etot; e += (long long)gridDim.x * 4) {
        int ie = (int)e;
        int s, d;
        if (ie < E) { s = ei[ie]; d = ei[E + ie]; }
        else { s = d = ie - E; }
        float4 av = *(const float4*)(expa + (size_t)ie * 4);
        const float* xs = xl1 + (size_t)s * 256;
        float* o = out + (size_t)d * 256;
        atomicAdd(o + lane,       xs[lane] * av.x);
        atomicAdd(o + 64 + lane,  xs[64 + lane] * av.y);
        atomicAdd(o + 128 + lane, xs[128 + lane] * av.z);
        atomicAdd(o + 192 + lane, xs[192 + lane] * av.w);
    }
}

// ---------- node pass 1: h1 = elu(bn1(out1/denom + bias1) + x@Wres) ----------
__global__ __launch_bounds__(256) void k_node1(const float* __restrict__ out1, const float* __restrict__ denom,
                                               const float* __restrict__ bias1,
                                               const float* __restrict__ x, const float* __restrict__ Wres,
                                               const float* __restrict__ g, const float* __restrict__ b,
                                               const float* __restrict__ m, const float* __restrict__ v,
                                               float* __restrict__ h1, int N) {
    __shared__ float sw[16 * 256];
    __shared__ float sx[32 * 16];
    int t = threadIdx.x;
#pragma unroll
    for (int k = 0; k < 16; k++) sw[k * 256 + t] = Wres[k * 256 + t];
    int n0 = blockIdx.x * 32;
    for (int i = t; i < 512; i += 256) {
        int n = n0 + (i >> 4);
        sx[i] = (n < N) ? x[(size_t)n * 16 + (i & 15)] : 0.f;
    }
    __syncthreads();
    float bias = bias1[t], gg = g[t], bb = b[t], mm = m[t];
    float inv = rsqrtf(v[t] + 1e-5f);
    int h = t >> 6;
    for (int ni = 0; ni < 32; ni++) {
        int n = n0 + ni;
        if (n >= N) break;
        float r = 0.f;
#pragma unroll
        for (int k = 0; k < 16; k++) r += sx[ni * 16 + k] * sw[k * 256 + t];
        float val = out1[(size_t)n * 256 + t] / (denom[(size_t)n * 4 + h] + 1e-16f) + bias;
        val = (val - mm) * inv * gg + bb;
        val += r;
        h1[(size_t)n * 256 + t] = elu_f(val);
    }
}

// ---------- xl2 = h1@Wl2+bl2, xr2 = h1@Wr2+br2 (register-tiled) ----------
__global__ __launch_bounds__(256) void k_xlr2(const float* __restrict__ h1,
                                              const float* __restrict__ Wl2, const float* __restrict__ bl2,
                                              const float* __restrict__ Wr2, const float* __restrict__ br2,
                                              float* __restrict__ xl2, float* __restrict__ xr2, int N) {
    __shared__ float sh[32][32];    // [kk][node]
    __shared__ float sw[32][128];   // [kk][col]
    int t = threadIdx.x;
    int tr = t >> 5, tc = t & 31;
    int n0 = blockIdx.x * 32;
    float acc[4][4];
#pragma unroll
    for (int i = 0; i < 4; i++)
#pragma unroll
        for (int j = 0; j < 4; j++) acc[i][j] = 0.f;
    for (int k0 = 0; k0 < 256; k0 += 32) {
        {
            int n = t >> 3, kk0 = (t & 7) * 4;
            int gn = n0 + n;
            float4 hv = make_float4(0.f, 0.f, 0.f, 0.f);
            if (gn < N) hv = *(const float4*)(h1 + (size_t)gn * 256 + k0 + kk0);
            sh[kk0 + 0][n] = hv.x; sh[kk0 + 1][n] = hv.y; sh[kk0 + 2][n] = hv.z; sh[kk0 + 3][n] = hv.w;
        }
        for (int i = t; i < 32 * 128; i += 256) {
            int kk = i >> 7, c = i & 127;
            sw[kk][c] = (c < 64) ? Wl2[(size_t)(k0 + kk) * 64 + c] : Wr2[(size_t)(k0 + kk) * 64 + (c - 64)];
        }
        __syncthreads();
#pragma unroll
        for (int kk = 0; kk < 32; kk++) {
            float4 hv = *(const float4*)&sh[kk][tr * 4];
            float4 wv = *(const float4*)&sw[kk][tc * 4];
            float hh[4] = { hv.x, hv.y, hv.z, hv.w };
            float wwv[4] = { wv.x, wv.y, wv.z, wv.w };
#pragma unroll
            for (int i = 0; i < 4; i++)
#pragma unroll
                for (int j = 0; j < 4; j++) acc[i][j] += hh[i] * wwv[j];
        }
        __syncthreads();
    }
#pragma unroll
    for (int i = 0; i < 4; i++) {
        int gn = n0 + tr * 4 + i;
        if (gn >= N) continue;
#pragma unroll
        for (int j = 0; j < 4; j++) {
            int c = tc * 4 + j;
            float vv = acc[i][j];
            if (c < 64) xl2[(size_t)gn * 64 + c] = vv + bl2[c];
            else        xr2[(size_t)gn * 64 + (c - 64)] = vv + br2[c - 64];
        }
    }
}

// ---------- conv2 attention logits + segment max ----------
__global__ __launch_bounds__(256) void k_alpha2(const float* __restrict__ xl2, const float* __restrict__ xr2,
                                                const int* __restrict__ ei, const float* __restrict__ ea,
                                                const float* __restrict__ ea_sum, const float* __restrict__ We2,
                                                const float* __restrict__ att2,
                                                float* __restrict__ alpha_out, unsigned* __restrict__ amax,
                                                int E, int N) {
    __shared__ float swe[8 * 64];
    int t = threadIdx.x;
    if (t < 512) swe[t] = We2[t];
    __syncthreads();
    int lane = t & 63, w = t >> 6;
    int Etot = E + N;
    for (long long e = (long long)blockIdx.x * 4 + w; e < Etot; e += (long long)gridDim.x * 4) {
        int ie = (int)e;
        int s, d;
        float eav[8];
        if (ie < E) {
            s = ei[ie]; d = ei[E + ie];
#pragma unroll
            for (int k = 0; k < 8; k++) eav[k] = ea[(size_t)ie * 8 + k];
        } else {
            s = d = ie - E;
            float invE = 1.f / (float)E;
#pragma unroll
            for (int k = 0; k < 8; k++) eav[k] = ea_sum[k] * invE;
        }
        float v = xl2[(size_t)s * 64 + lane] + xr2[(size_t)d * 64 + lane];
#pragma unroll
        for (int k = 0; k < 8; k++) v += eav[k] * swe[k * 64 + lane];
        v = v > 0.f ? v : 0.2f * v;
        float p = v * att2[lane];
#pragma unroll
        for (int o = 32; o; o >>= 1) p += __shfl_xor(p, o, 64);
        if (lane == 0) {
            alpha_out[ie] = p;
            atomicMax(amax + d, fkey(p));
        }
    }
}

// ---------- conv2 exp + denom ----------
__global__ __launch_bounds__(256) void k_exp2(float* __restrict__ alpha, const int* __restrict__ ei,
                                              const unsigned* __restrict__ amax, float* __restrict__ denom,
                                              int E, int N) {
    int e = blockIdx.x * blockDim.x + threadIdx.x;
    if (e >= E + N) return;
    int d = (e < E) ? ei[E + e] : (e - E);
    float m = funkey(amax[d]);
    float v = expf(alpha[e] - m);
    alpha[e] = v;
    atomicAdd(denom + d, v);
}

// ---------- conv2 aggregation ----------
__global__ __launch_bounds__(256) void k_agg2(const float* __restrict__ xl2, const float* __restrict__ expa,
                                              const int* __restrict__ ei, float* __restrict__ out,
                                              int E, int N) {
    int t = threadIdx.x, lane = t & 63, w = t >> 6;
    int Etot = E + N;
    for (long long e = (long long)blockIdx.x * 4 + w; e < Etot; e += (long long)gridDim.x * 4) {
        int ie = (int)e;
        int s, d;
        if (ie < E) { s = ei[ie]; d = ei[E + ie]; }
        else { s = d = ie - E; }
        float a = expa[ie];
        atomicAdd(out + (size_t)d * 64 + lane, xl2[(size_t)s * 64 + lane] * a);
    }
}

// ---------- node pass 2: h2 = elu(bn2(out2/denom2 + bias2)) ----------
__global__ __launch_bounds__(256) void k_node2(const float* __restrict__ out2, const float* __restrict__ denom,
                                               const float* __restrict__ bias2,
                                               const float* __restrict__ g, const float* __restrict__ b,
                                               const float* __restrict__ m, const float* __restrict__ v,
                                               float* __restrict__ h2, int N) {
    int i = blockIdx.x * blockDim.x + threadIdx.x;
    if (i >= N * 64) return;
    int n = i >> 6, c = i & 63;
    float val = out2[i] / (denom[n] + 1e-16f) + bias2[c];
    val = (val - m[c]) * rsqrtf(v[c] + 1e-5f) * g[c] + b[c];
    h2[i] = elu_f(val);
}

// ---------- edge MLP head ----------
__global__ __launch_bounds__(256) void k_mlp(const float* __restrict__ h2, const int* __restrict__ ei,
                                             const float* __restrict__ ea,
                                             const float* __restrict__ Wm1, const float* __restrict__ bm1,
                                             const float* __restrict__ Wm2, const float* __restrict__ bm2,
                                             const float* __restrict__ Wm3, const float* __restrict__ bm3,
                                             float* __restrict__ out, int E) {
    __shared__ float sw1[136 * 64];
    __shared__ float sw2[64 * 32];
    __shared__ float sw3[32];
    __shared__ float ser[4][136];
    __shared__ float sz1[4][64];
    int t = threadIdx.x;
    for (int i = t; i < 136 * 64; i += 256) sw1[i] = Wm1[i];
    for (int i = t; i < 64 * 32; i += 256) sw2[i] = Wm2[i];
    if (t < 32) sw3[t] = Wm3[t];
    __syncthreads();
    int lane = t & 63, w = t >> 6;
    float b3 = bm3[0];
    long long Eg = (E + 3) >> 2;
    for (long long gidx = blockIdx.x; gidx < Eg; gidx += gridDim.x) {
        long long e = gidx * 4 + w;
        bool active = e < E;
        int r = 0, c = 0;
        if (active) { r = ei[e]; c = ei[E + e]; }
        if (active) {
            ser[w][lane] = h2[(size_t)r * 64 + lane];
            ser[w][64 + lane] = h2[(size_t)c * 64 + lane];
            if (lane < 8) ser[w][128 + lane] = ea[(size_t)e * 8 + lane];
        }
        __syncthreads();
        float acc = bm1[lane];
#pragma unroll 8
        for (int k = 0; k < 136; k++) acc += ser[w][k] * sw1[k * 64 + lane];
        acc = gelu_f(acc);
        sz1[w][lane] = acc;
        __syncthreads();
        int half = lane >> 5, c2 = lane & 31;
        float a2 = 0.f;
#pragma unroll
        for (int kk = 0; kk < 32; kk++) {
            int k = half * 32 + kk;
            a2 += sz1[w][k] * sw2[k * 32 + c2];
        }
        a2 += __shfl_xor(a2, 32, 64);
        a2 = gelu_f(a2 + bm2[c2]);
        float p = (lane < 32) ? a2 * sw3[lane] : 0.f;
#pragma unroll
        for (int o = 16; o; o >>= 1) p += __shfl_xor(p, o, 64);
        if (active && lane == 0) out[e] = 1.f / (1.f + expf(-(p + b3)));
    }
}

extern "C" void kernel_launch(void* const* d_in, const int* in_sizes, int n_in,
                              void* d_out, int out_size, void* d_ws, size_t ws_size,
                              hipStream_t stream) {
    const float* x    = (const float*)d_in[0];
    const int*   ei   = (const int*)d_in[1];
    const float* ea   = (const float*)d_in[2];
    const float* Wl1  = (const float*)d_in[3];
    const float* bl1  = (const float*)d_in[4];
    const float* Wr1  = (const float*)d_in[5];
    const float* br1  = (const float*)d_in[6];
    const float* We1  = (const float*)d_in[7];
    const float* att1 = (const float*)d_in[8];
    const float* bias1= (const float*)d_in[9];
    const float* Wl2  = (const float*)d_in[10];
    const float* bl2  = (const float*)d_in[11];
    const float* Wr2  = (const float*)d_in[12];
    const float* br2  = (const float*)d_in[13];
    const float* We2  = (const float*)d_in[14];
    const float* att2 = (const float*)d_in[15];
    const float* bias2= (const float*)d_in[16];
    const float* bn1g = (const float*)d_in[17];
    const float* bn1b = (const float*)d_in[18];
    const float* bn1m = (const float*)d_in[19];
    const float* bn1v = (const float*)d_in[20];
    const float* bn2g = (const float*)d_in[21];
    const float* bn2b = (const float*)d_in[22];
    const float* bn2m = (const float*)d_in[23];
    const float* bn2v = (const float*)d_in[24];
    const float* Wres = (const float*)d_in[25];
    const float* Wm1  = (const float*)d_in[26];
    const float* bm1  = (const float*)d_in[27];
    const float* Wm2  = (const float*)d_in[28];
    const float* bm2  = (const float*)d_in[29];
    const float* Wm3  = (const float*)d_in[30];
    const float* bm3  = (const float*)d_in[31];
    float* out = (float*)d_out;
    float* ws = (float*)d_ws;

    const int N = NN, E = EE, Etot = ETOT;

    // workspace layout (floats)
    float*    ea_sum = ws;                                        // 8 (pad 16)
    unsigned* amax1  = (unsigned*)(ws + 16);                      // 4N
    float*    denom1 = ws + 16 + (size_t)4 * N;                   // 4N
    unsigned* amax2  = (unsigned*)(ws + 16 + (size_t)8 * N);      // N
    float*    denom2 = ws + 16 + (size_t)9 * N;                   // N
    float*    expa1  = ws + 16 + (size_t)10 * N;                  // 4*Etot
    float*    expa2  = ws + 16 + (size_t)14 * N + (size_t)4 * E;  // Etot
    float*    A      = ws + 16 + (size_t)15 * N + (size_t)5 * E;  // 256N
    float*    B      = A + (size_t)256 * N;                       // 256N
    float*    Cacc   = B + (size_t)256 * N;                       // 256N

    float* xl1 = A;
    float* xr1 = B;
    float* h1  = B;                    // reuses xr1 (dead after k_alpha1)
    float* xl2 = A;                    // reuses xl1 (dead after k_agg1)
    float* xr2 = A + (size_t)64 * N;
    float* out2= A + (size_t)128 * N;
    float* h2  = A + (size_t)192 * N;

    hipMemsetAsync(ws, 0, (size_t)(16 + (size_t)10 * N) * sizeof(float), stream);
    hipMemsetAsync(Cacc, 0, (size_t)256 * N * sizeof(float), stream);

    k_ea_reduce<<<256, 256, 0, stream>>>(ea, ea_sum, E);
    k_ntrans1<<<(N + 31) / 32, 256, 0, stream>>>(x, Wl1, bl1, Wr1, br1, xl1, xr1, N);
    k_alpha1<<<2048, 256, 0, stream>>>(xl1, xr1, ei, ea, ea_sum, We1, att1, expa1, amax1, E, N);
    k_exp1<<<(Etot * 4 + 255) / 256, 256, 0, stream>>>(expa1, ei, amax1, denom1, E, N);
    k_agg1<<<2048, 256, 0, stream>>>(xl1, expa1, ei, Cacc, E, N);
    k_node1<<<(N + 31) / 32, 256, 0, stream>>>(Cacc, denom1, bias1, x, Wres, bn1g, bn1b, bn1m, bn1v, h1, N);
    hipMemsetAsync(out2, 0, (size_t)64 * N * sizeof(float), stream);
    k_xlr2<<<(N + 31) / 32, 256, 0, stream>>>(h1, Wl2, bl2, Wr2, br2, xl2, xr2, N);
    k_alpha2<<<2048, 256, 0, stream>>>(xl2, xr2, ei, ea, ea_sum, We2, att2, expa2, amax2, E, N);
    k_exp2<<<(Etot + 255) / 256, 256, 0, stream>>>(expa2, ei, amax2, denom2, E, N);
    k_agg2<<<2048, 256, 0, stream>>>(xl2, expa2, ei, out2, E, N);
    k_node2<<<((size_t)N * 64 + 255) / 256, 256, 0, stream>>>(out2, denom2, bias2, bn2g, bn2b, bn2m, bn2v, h2, N);
    k_mlp<<<2048, 256, 0, stream>>>(h2, ei, ea, Wm1, bm1, Wm2, bm2, Wm3, bm3, out, E);
}

// Round 2
// 1106.356 us; speedup vs baseline: 1.2712x; 1.2712x over previous
//
#include <hip/hip_runtime.h>
#include <hip/hip_bf16.h>
#include <math.h>

#define NN 50000
#define EE 400000
#define ETOT (NN + EE)

// ---------- helpers ----------
__device__ __forceinline__ unsigned fkey(float f) {
    unsigned u = __float_as_uint(f);
    return (u & 0x80000000u) ? ~u : (u | 0x80000000u);
}
__device__ __forceinline__ float funkey(unsigned u) {
    return __uint_as_float((u & 0x80000000u) ? (u & 0x7fffffffu) : ~u);
}
__device__ __forceinline__ float gelu_f(float x) {
    return 0.5f * x * (1.f + erff(x * 0.7071067811865476f));
}
__device__ __forceinline__ float elu_f(float x) {
    return x > 0.f ? x : expm1f(x);
}

// ---------- ea mean (sum) ----------
__global__ __launch_bounds__(256) void k_ea_reduce(const float* __restrict__ ea,
                                                   float* __restrict__ ea_sum, int E) {
    float s[8];
#pragma unroll
    for (int i = 0; i < 8; i++) s[i] = 0.f;
    for (int e = blockIdx.x * blockDim.x + threadIdx.x; e < E; e += gridDim.x * blockDim.x) {
        const float4* p = (const float4*)(ea + (size_t)e * 8);
        float4 a = p[0], b = p[1];
        s[0] += a.x; s[1] += a.y; s[2] += a.z; s[3] += a.w;
        s[4] += b.x; s[5] += b.y; s[6] += b.z; s[7] += b.w;
    }
#pragma unroll
    for (int o = 32; o; o >>= 1)
#pragma unroll
        for (int i = 0; i < 8; i++) s[i] += __shfl_xor(s[i], o, 64);
    __shared__ float sh[4][8];
    int lane = threadIdx.x & 63, w = threadIdx.x >> 6;
    if (lane == 0)
#pragma unroll
        for (int i = 0; i < 8; i++) sh[w][i] = s[i];
    __syncthreads();
    if (threadIdx.x < 8) {
        float v = sh[0][threadIdx.x] + sh[1][threadIdx.x] + sh[2][threadIdx.x] + sh[3][threadIdx.x];
        atomicAdd(ea_sum + threadIdx.x, v);
    }
}

// ---------- node transform 1: xl1 = x@Wl1+bl1, xr1 = x@Wr1+br1 ----------
__global__ __launch_bounds__(256) void k_ntrans1(const float* __restrict__ x,
                                                 const float* __restrict__ Wl, const float* __restrict__ bl,
                                                 const float* __restrict__ Wr, const float* __restrict__ br,
                                                 float* __restrict__ xl1, float* __restrict__ xr1, int N) {
    __shared__ float swl[16 * 256];
    __shared__ float swr[16 * 256];
    __shared__ float sx[32 * 16];
    int t = threadIdx.x;
#pragma unroll
    for (int k = 0; k < 16; k++) { swl[k * 256 + t] = Wl[k * 256 + t]; swr[k * 256 + t] = Wr[k * 256 + t]; }
    int n0 = blockIdx.x * 32;
    for (int i = t; i < 32 * 16; i += 256) {
        int n = n0 + (i >> 4);
        sx[i] = (n < N) ? x[(size_t)n * 16 + (i & 15)] : 0.f;
    }
    __syncthreads();
    float bL = bl[t], bR = br[t];
    for (int ni = 0; ni < 32; ni++) {
        int n = n0 + ni;
        if (n >= N) break;
        float al = bL, ar = bR;
#pragma unroll
        for (int k = 0; k < 16; k++) {
            float xv = sx[ni * 16 + k];
            al += xv * swl[k * 256 + t];
            ar += xv * swr[k * 256 + t];
        }
        xl1[(size_t)n * 256 + t] = al;
        xr1[(size_t)n * 256 + t] = ar;
    }
}

// ---------- conv1 attention logits + segment max ----------
__global__ __launch_bounds__(256) void k_alpha1(const float* __restrict__ xl1, const float* __restrict__ xr1,
                                                const int* __restrict__ ei, const float* __restrict__ ea,
                                                const float* __restrict__ ea_sum, const float* __restrict__ We1,
                                                const float* __restrict__ att1,
                                                float* __restrict__ alpha_out, unsigned* __restrict__ amax,
                                                int E, int N) {
    __shared__ float swe[8 * 256];
    int t = threadIdx.x;
    for (int i = t; i < 8 * 256; i += 256) swe[i] = We1[i];
    __syncthreads();
    int lane = t & 63, w = t >> 6;
    int Etot = E + N;
    for (long long e = (long long)blockIdx.x * 4 + w; e < Etot; e += (long long)gridDim.x * 4) {
        int ie = (int)e;
        int s, d;
        float eav[8];
        if (ie < E) {
            s = ei[ie]; d = ei[E + ie];
#pragma unroll
            for (int k = 0; k < 8; k++) eav[k] = ea[(size_t)ie * 8 + k];
        } else {
            s = d = ie - E;
            float invE = 1.f / (float)E;
#pragma unroll
            for (int k = 0; k < 8; k++) eav[k] = ea_sum[k] * invE;
        }
        float p[4];
#pragma unroll
        for (int h = 0; h < 4; h++) {
            int c = h * 64 + lane;
            float v = xl1[(size_t)s * 256 + c] + xr1[(size_t)d * 256 + c];
#pragma unroll
            for (int k = 0; k < 8; k++) v += eav[k] * swe[k * 256 + c];
            v = v > 0.f ? v : 0.2f * v;
            p[h] = v * att1[c];
        }
#pragma unroll
        for (int o = 32; o; o >>= 1) {
            p[0] += __shfl_xor(p[0], o, 64);
            p[1] += __shfl_xor(p[1], o, 64);
            p[2] += __shfl_xor(p[2], o, 64);
            p[3] += __shfl_xor(p[3], o, 64);
        }
        if (lane < 4) {
            alpha_out[(size_t)ie * 4 + lane] = p[lane];
            atomicMax(amax + (size_t)d * 4 + lane, fkey(p[lane]));
        }
    }
}

// ---------- conv1 exp + denom ----------
__global__ __launch_bounds__(256) void k_exp1(float* __restrict__ alpha, const int* __restrict__ ei,
                                              const unsigned* __restrict__ amax, float* __restrict__ denom,
                                              int E, int N) {
    int i = blockIdx.x * blockDim.x + threadIdx.x;
    int tot = (E + N) * 4;
    if (i >= tot) return;
    int e = i >> 2, h = i & 3;
    int d = (e < E) ? ei[E + e] : (e - E);
    float m = funkey(amax[(size_t)d * 4 + h]);
    float v = expf(alpha[i] - m);
    alpha[i] = v;
    atomicAdd(denom + (size_t)d * 4 + h, v);
}

// ---------- conv1 aggregation: out1[d] += xl1[s] * expa ----------
__global__ __launch_bounds__(256) void k_agg1(const float* __restrict__ xl1, const float* __restrict__ expa,
                                              const int* __restrict__ ei, float* __restrict__ out,
                                              int E, int N) {
    int t = threadIdx.x, lane = t & 63, w = t >> 6;
    int Etot = E + N;
    for (long long e = (long long)blockIdx.x * 4 + w; e < Etot; e += (long long)gridDim.x * 4) {
        int ie = (int)e;
        int s, d;
        if (ie < E) { s = ei[ie]; d = ei[E + ie]; }
        else { s = d = ie - E; }
        float4 av = *(const float4*)(expa + (size_t)ie * 4);
        const float* xs = xl1 + (size_t)s * 256;
        float* o = out + (size_t)d * 256;
        atomicAdd(o + lane,       xs[lane] * av.x);
        atomicAdd(o + 64 + lane,  xs[64 + lane] * av.y);
        atomicAdd(o + 128 + lane, xs[128 + lane] * av.z);
        atomicAdd(o + 192 + lane, xs[192 + lane] * av.w);
    }
}

// ---------- node pass 1: h1 = elu(bn1(out1/denom + bias1) + x@Wres) ----------
__global__ __launch_bounds__(256) void k_node1(const float* __restrict__ out1, const float* __restrict__ denom,
                                               const float* __restrict__ bias1,
                                               const float* __restrict__ x, const float* __restrict__ Wres,
                                               const float* __restrict__ g, const float* __restrict__ b,
                                               const float* __restrict__ m, const float* __restrict__ v,
                                               float* __restrict__ h1, int N) {
    __shared__ float sw[16 * 256];
    __shared__ float sx[32 * 16];
    int t = threadIdx.x;
#pragma unroll
    for (int k = 0; k < 16; k++) sw[k * 256 + t] = Wres[k * 256 + t];
    int n0 = blockIdx.x * 32;
    for (int i = t; i < 512; i += 256) {
        int n = n0 + (i >> 4);
        sx[i] = (n < N) ? x[(size_t)n * 16 + (i & 15)] : 0.f;
    }
    __syncthreads();
    float bias = bias1[t], gg = g[t], bb = b[t], mm = m[t];
    float inv = rsqrtf(v[t] + 1e-5f);
    int h = t >> 6;
    for (int ni = 0; ni < 32; ni++) {
        int n = n0 + ni;
        if (n >= N) break;
        float r = 0.f;
#pragma unroll
        for (int k = 0; k < 16; k++) r += sx[ni * 16 + k] * sw[k * 256 + t];
        float val = out1[(size_t)n * 256 + t] / (denom[(size_t)n * 4 + h] + 1e-16f) + bias;
        val = (val - mm) * inv * gg + bb;
        val += r;
        h1[(size_t)n * 256 + t] = elu_f(val);
    }
}

// ---------- xl2 = h1@Wl2+bl2, xr2 = h1@Wr2+br2 (register-tiled) ----------
__global__ __launch_bounds__(256) void k_xlr2(const float* __restrict__ h1,
                                              const float* __restrict__ Wl2, const float* __restrict__ bl2,
                                              const float* __restrict__ Wr2, const float* __restrict__ br2,
                                              float* __restrict__ xl2, float* __restrict__ xr2, int N) {
    __shared__ float sh[32][32];    // [kk][node]
    __shared__ float sw[32][128];   // [kk][col]
    int t = threadIdx.x;
    int tr = t >> 5, tc = t & 31;
    int n0 = blockIdx.x * 32;
    float acc[4][4];
#pragma unroll
    for (int i = 0; i < 4; i++)
#pragma unroll
        for (int j = 0; j < 4; j++) acc[i][j] = 0.f;
    for (int k0 = 0; k0 < 256; k0 += 32) {
        {
            int n = t >> 3, kk0 = (t & 7) * 4;
            int gn = n0 + n;
            float4 hv = make_float4(0.f, 0.f, 0.f, 0.f);
            if (gn < N) hv = *(const float4*)(h1 + (size_t)gn * 256 + k0 + kk0);
            sh[kk0 + 0][n] = hv.x; sh[kk0 + 1][n] = hv.y; sh[kk0 + 2][n] = hv.z; sh[kk0 + 3][n] = hv.w;
        }
        for (int i = t; i < 32 * 128; i += 256) {
            int kk = i >> 7, c = i & 127;
            sw[kk][c] = (c < 64) ? Wl2[(size_t)(k0 + kk) * 64 + c] : Wr2[(size_t)(k0 + kk) * 64 + (c - 64)];
        }
        __syncthreads();
#pragma unroll
        for (int kk = 0; kk < 32; kk++) {
            float4 hv = *(const float4*)&sh[kk][tr * 4];
            float4 wv = *(const float4*)&sw[kk][tc * 4];
            float hh[4] = { hv.x, hv.y, hv.z, hv.w };
            float wwv[4] = { wv.x, wv.y, wv.z, wv.w };
#pragma unroll
            for (int i = 0; i < 4; i++)
#pragma unroll
                for (int j = 0; j < 4; j++) acc[i][j] += hh[i] * wwv[j];
        }
        __syncthreads();
    }
#pragma unroll
    for (int i = 0; i < 4; i++) {
        int gn = n0 + tr * 4 + i;
        if (gn >= N) continue;
#pragma unroll
        for (int j = 0; j < 4; j++) {
            int c = tc * 4 + j;
            float vv = acc[i][j];
            if (c < 64) xl2[(size_t)gn * 64 + c] = vv + bl2[c];
            else        xr2[(size_t)gn * 64 + (c - 64)] = vv + br2[c - 64];
        }
    }
}

// ---------- conv2 attention logits + segment max ----------
__global__ __launch_bounds__(256) void k_alpha2(const float* __restrict__ xl2, const float* __restrict__ xr2,
                                                const int* __restrict__ ei, const float* __restrict__ ea,
                                                const float* __restrict__ ea_sum, const float* __restrict__ We2,
                                                const float* __restrict__ att2,
                                                float* __restrict__ alpha_out, unsigned* __restrict__ amax,
                                                int E, int N) {
    __shared__ float swe[8 * 64];
    int t = threadIdx.x;
    if (t < 512) swe[t] = We2[t];
    __syncthreads();
    int lane = t & 63, w = t >> 6;
    int Etot = E + N;
    for (long long e = (long long)blockIdx.x * 4 + w; e < Etot; e += (long long)gridDim.x * 4) {
        int ie = (int)e;
        int s, d;
        float eav[8];
        if (ie < E) {
            s = ei[ie]; d = ei[E + ie];
#pragma unroll
            for (int k = 0; k < 8; k++) eav[k] = ea[(size_t)ie * 8 + k];
        } else {
            s = d = ie - E;
            float invE = 1.f / (float)E;
#pragma unroll
            for (int k = 0; k < 8; k++) eav[k] = ea_sum[k] * invE;
        }
        float v = xl2[(size_t)s * 64 + lane] + xr2[(size_t)d * 64 + lane];
#pragma unroll
        for (int k = 0; k < 8; k++) v += eav[k] * swe[k * 64 + lane];
        v = v > 0.f ? v : 0.2f * v;
        float p = v * att2[lane];
#pragma unroll
        for (int o = 32; o; o >>= 1) p += __shfl_xor(p, o, 64);
        if (lane == 0) {
            alpha_out[ie] = p;
            atomicMax(amax + d, fkey(p));
        }
    }
}

// ---------- conv2 exp + denom ----------
__global__ __launch_bounds__(256) void k_exp2(float* __restrict__ alpha, const int* __restrict__ ei,
                                              const unsigned* __restrict__ amax, float* __restrict__ denom,
                                              int E, int N) {
    int e = blockIdx.x * blockDim.x + threadIdx.x;
    if (e >= E + N) return;
    int d = (e < E) ? ei[E + e] : (e - E);
    float m = funkey(amax[d]);
    float v = expf(alpha[e] - m);
    alpha[e] = v;
    atomicAdd(denom + d, v);
}

// ---------- conv2 aggregation ----------
__global__ __launch_bounds__(256) void k_agg2(const float* __restrict__ xl2, const float* __restrict__ expa,
                                              const int* __restrict__ ei, float* __restrict__ out,
                                              int E, int N) {
    int t = threadIdx.x, lane = t & 63, w = t >> 6;
    int Etot = E + N;
    for (long long e = (long long)blockIdx.x * 4 + w; e < Etot; e += (long long)gridDim.x * 4) {
        int ie = (int)e;
        int s, d;
        if (ie < E) { s = ei[ie]; d = ei[E + ie]; }
        else { s = d = ie - E; }
        float a = expa[ie];
        atomicAdd(out + (size_t)d * 64 + lane, xl2[(size_t)s * 64 + lane] * a);
    }
}

// ---------- node pass 2: h2 = elu(bn2(out2/denom2 + bias2)) ----------
__global__ __launch_bounds__(256) void k_node2(const float* __restrict__ out2, const float* __restrict__ denom,
                                               const float* __restrict__ bias2,
                                               const float* __restrict__ g, const float* __restrict__ b,
                                               const float* __restrict__ m, const float* __restrict__ v,
                                               float* __restrict__ h2, int N) {
    int i = blockIdx.x * blockDim.x + threadIdx.x;
    if (i >= N * 64) return;
    int n = i >> 6, c = i & 63;
    float val = out2[i] / (denom[n] + 1e-16f) + bias2[c];
    val = (val - m[c]) * rsqrtf(v[c] + 1e-5f) * g[c] + b[c];
    h2[i] = elu_f(val);
}

// ---------- edge MLP head: tiled GEMM, 64 edges per block ----------
// er[64][136] staged in LDS (pad to 140), W1/W2/W3 in LDS.
// layer1: 4x4 register tile per thread (16 threads x, 16 threads y).
// z1 written back into er region (er dead after GEMM1). z2 into cols 96+.
__global__ __launch_bounds__(256) void k_mlp(const float* __restrict__ h2, const int* __restrict__ ei,
                                             const float* __restrict__ ea,
                                             const float* __restrict__ Wm1, const float* __restrict__ bm1,
                                             const float* __restrict__ Wm2, const float* __restrict__ bm2,
                                             const float* __restrict__ Wm3, const float* __restrict__ bm3,
                                             float* __restrict__ out, int E) {
    __shared__ float sw1[136 * 64];
    __shared__ float sw2[64 * 32];
    __shared__ float sw3[32];
    __shared__ int sre[64], sce[64];
    __shared__ float sa[64 * 140];
    int t = threadIdx.x;
    for (int i = t; i < 136 * 64; i += 256) sw1[i] = Wm1[i];
    for (int i = t; i < 64 * 32; i += 256) sw2[i] = Wm2[i];
    if (t < 32) sw3[t] = Wm3[t];
    int e0 = blockIdx.x * 64;
    if (t < 64) {
        int e = e0 + t;
        if (e < E) { sre[t] = ei[e]; sce[t] = ei[E + e]; }
        else { sre[t] = 0; sce[t] = 0; }
    }
    __syncthreads();
    // stage er tile: [h2[r] | h2[c] | ea[e]] = 136 floats = 34 float4 per edge
    for (int i = t; i < 64 * 34; i += 256) {
        int el = i / 34, q = i - el * 34;
        float4 v;
        if (q < 16)      v = *(const float4*)(h2 + (size_t)sre[el] * 64 + q * 4);
        else if (q < 32) v = *(const float4*)(h2 + (size_t)sce[el] * 64 + (q - 16) * 4);
        else             v = *(const float4*)(ea + (size_t)(e0 + el) * 8 + (q - 32) * 4);
        *(float4*)(sa + el * 140 + q * 4) = v;
    }
    __syncthreads();
    int tr = t >> 4, tc = t & 15;       // tr: edge group (4 edges), tc: col group (4 cols)
    // ---- layer 1: [64,136] @ [136,64] ----
    float acc[4][4];
#pragma unroll
    for (int j = 0; j < 4; j++) {
        float bv = bm1[tc * 4 + j];
#pragma unroll
        for (int i = 0; i < 4; i++) acc[i][j] = bv;
    }
    for (int k = 0; k < 136; k++) {
        float4 bv = *(const float4*)(sw1 + k * 64 + tc * 4);
        float a0 = sa[(tr * 4 + 0) * 140 + k];
        float a1 = sa[(tr * 4 + 1) * 140 + k];
        float a2 = sa[(tr * 4 + 2) * 140 + k];
        float a3 = sa[(tr * 4 + 3) * 140 + k];
        acc[0][0] += a0 * bv.x; acc[0][1] += a0 * bv.y; acc[0][2] += a0 * bv.z; acc[0][3] += a0 * bv.w;
        acc[1][0] += a1 * bv.x; acc[1][1] += a1 * bv.y; acc[1][2] += a1 * bv.z; acc[1][3] += a1 * bv.w;
        acc[2][0] += a2 * bv.x; acc[2][1] += a2 * bv.y; acc[2][2] += a2 * bv.z; acc[2][3] += a2 * bv.w;
        acc[3][0] += a3 * bv.x; acc[3][1] += a3 * bv.y; acc[3][2] += a3 * bv.z; acc[3][3] += a3 * bv.w;
    }
    __syncthreads();   // all reads of er done; reuse sa cols 0..63 for z1
#pragma unroll
    for (int i = 0; i < 4; i++) {
        float4 z;
        z.x = gelu_f(acc[i][0]); z.y = gelu_f(acc[i][1]);
        z.z = gelu_f(acc[i][2]); z.w = gelu_f(acc[i][3]);
        *(float4*)(sa + (tr * 4 + i) * 140 + tc * 4) = z;
    }
    __syncthreads();
    // ---- layer 2: [64,64] @ [64,32] ---- thread: 4 edges x 2 cols
    float acc2[4][2];
#pragma unroll
    for (int j = 0; j < 2; j++) {
        float bv = bm2[tc * 2 + j];
#pragma unroll
        for (int i = 0; i < 4; i++) acc2[i][j] = bv;
    }
    for (int k = 0; k < 64; k++) {
        float2 bv = *(const float2*)(sw2 + k * 32 + tc * 2);
        float a0 = sa[(tr * 4 + 0) * 140 + k];
        float a1 = sa[(tr * 4 + 1) * 140 + k];
        float a2 = sa[(tr * 4 + 2) * 140 + k];
        float a3 = sa[(tr * 4 + 3) * 140 + k];
        acc2[0][0] += a0 * bv.x; acc2[0][1] += a0 * bv.y;
        acc2[1][0] += a1 * bv.x; acc2[1][1] += a1 * bv.y;
        acc2[2][0] += a2 * bv.x; acc2[2][1] += a2 * bv.y;
        acc2[3][0] += a3 * bv.x; acc2[3][1] += a3 * bv.y;
    }
    __syncthreads();   // z1 reads done; write z2 into cols 96..127
#pragma unroll
    for (int i = 0; i < 4; i++)
#pragma unroll
        for (int j = 0; j < 2; j++)
            sa[(tr * 4 + i) * 140 + 96 + tc * 2 + j] = gelu_f(acc2[i][j]);
    __syncthreads();
    // ---- layer 3: [64,32] @ [32,1] + sigmoid ----
    if (t < 64) {
        float s = bm3[0];
#pragma unroll
        for (int k = 0; k < 32; k++) s += sa[t * 140 + 96 + k] * sw3[k];
        int e = e0 + t;
        if (e < E) out[e] = 1.f / (1.f + expf(-s));
    }
}

extern "C" void kernel_launch(void* const* d_in, const int* in_sizes, int n_in,
                              void* d_out, int out_size, void* d_ws, size_t ws_size,
                              hipStream_t stream) {
    const float* x    = (const float*)d_in[0];
    const int*   ei   = (const int*)d_in[1];
    const float* ea   = (const float*)d_in[2];
    const float* Wl1  = (const float*)d_in[3];
    const float* bl1  = (const float*)d_in[4];
    const float* Wr1  = (const float*)d_in[5];
    const float* br1  = (const float*)d_in[6];
    const float* We1  = (const float*)d_in[7];
    const float* att1 = (const float*)d_in[8];
    const float* bias1= (const float*)d_in[9];
    const float* Wl2  = (const float*)d_in[10];
    const float* bl2  = (const float*)d_in[11];
    const float* Wr2  = (const float*)d_in[12];
    const float* br2  = (const float*)d_in[13];
    const float* We2  = (const float*)d_in[14];
    const float* att2 = (const float*)d_in[15];
    const float* bias2= (const float*)d_in[16];
    const float* bn1g = (const float*)d_in[17];
    const float* bn1b = (const float*)d_in[18];
    const float* bn1m = (const float*)d_in[19];
    const float* bn1v = (const float*)d_in[20];
    const float* bn2g = (const float*)d_in[21];
    const float* bn2b = (const float*)d_in[22];
    const float* bn2m = (const float*)d_in[23];
    const float* bn2v = (const float*)d_in[24];
    const float* Wres = (const float*)d_in[25];
    const float* Wm1  = (const float*)d_in[26];
    const float* bm1  = (const float*)d_in[27];
    const float* Wm2  = (const float*)d_in[28];
    const float* bm2  = (const float*)d_in[29];
    const float* Wm3  = (const float*)d_in[30];
    const float* bm3  = (const float*)d_in[31];
    float* out = (float*)d_out;
    float* ws = (float*)d_ws;

    const int N = NN, E = EE, Etot = ETOT;

    // workspace layout (floats)
    float*    ea_sum = ws;                                        // 8 (pad 16)
    unsigned* amax1  = (unsigned*)(ws + 16);                      // 4N
    float*    denom1 = ws + 16 + (size_t)4 * N;                   // 4N
    unsigned* amax2  = (unsigned*)(ws + 16 + (size_t)8 * N);      // N
    float*    denom2 = ws + 16 + (size_t)9 * N;                   // N
    float*    expa1  = ws + 16 + (size_t)10 * N;                  // 4*Etot
    float*    expa2  = ws + 16 + (size_t)14 * N + (size_t)4 * E;  // Etot
    float*    A      = ws + 16 + (size_t)15 * N + (size_t)5 * E;  // 256N
    float*    B      = A + (size_t)256 * N;                       // 256N
    float*    Cacc   = B + (size_t)256 * N;                       // 256N

    float* xl1 = A;
    float* xr1 = B;
    float* h1  = B;                    // reuses xr1 (dead after k_alpha1)
    float* xl2 = A;                    // reuses xl1 (dead after k_agg1)
    float* xr2 = A + (size_t)64 * N;
    float* out2= A + (size_t)128 * N;
    float* h2  = A + (size_t)192 * N;

    hipMemsetAsync(ws, 0, (size_t)(16 + (size_t)10 * N) * sizeof(float), stream);
    hipMemsetAsync(Cacc, 0, (size_t)256 * N * sizeof(float), stream);

    k_ea_reduce<<<256, 256, 0, stream>>>(ea, ea_sum, E);
    k_ntrans1<<<(N + 31) / 32, 256, 0, stream>>>(x, Wl1, bl1, Wr1, br1, xl1, xr1, N);
    k_alpha1<<<2048, 256, 0, stream>>>(xl1, xr1, ei, ea, ea_sum, We1, att1, expa1, amax1, E, N);
    k_exp1<<<(Etot * 4 + 255) / 256, 256, 0, stream>>>(expa1, ei, amax1, denom1, E, N);
    k_agg1<<<2048, 256, 0, stream>>>(xl1, expa1, ei, Cacc, E, N);
    k_node1<<<(N + 31) / 32, 256, 0, stream>>>(Cacc, denom1, bias1, x, Wres, bn1g, bn1b, bn1m, bn1v, h1, N);
    hipMemsetAsync(out2, 0, (size_t)64 * N * sizeof(float), stream);
    k_xlr2<<<(N + 31) / 32, 256, 0, stream>>>(h1, Wl2, bl2, Wr2, br2, xl2, xr2, N);
    k_alpha2<<<2048, 256, 0, stream>>>(xl2, xr2, ei, ea, ea_sum, We2, att2, expa2, amax2, E, N);
    k_exp2<<<(Etot + 255) / 256, 256, 0, stream>>>(expa2, ei, amax2, denom2, E, N);
    k_agg2<<<2048, 256, 0, stream>>>(xl2, expa2, ei, out2, E, N);
    k_node2<<<((size_t)N * 64 + 255) / 256, 256, 0, stream>>>(out2, denom2, bias2, bn2g, bn2b, bn2m, bn2v, h2, N);
    k_mlp<<<(E + 63) / 64, 256, 0, stream>>>(h2, ei, ea, Wm1, bm1, Wm2, bm2, Wm3, bm3, out, E);
}

// Round 3
// 949.903 us; speedup vs baseline: 1.4805x; 1.1647x over previous
//
#include <hip/hip_runtime.h>
#include <hip/hip_bf16.h>
#include <math.h>

#define NN 50000
#define EE 400000
#define ETOT (NN + EE)

// ---------- helpers ----------
__device__ __forceinline__ float gelu_f(float x) {
    return 0.5f * x * (1.f + erff(x * 0.7071067811865476f));
}
__device__ __forceinline__ float elu_f(float x) {
    return x > 0.f ? x : expm1f(x);
}

// ---------- ea mean (sum) ----------
__global__ __launch_bounds__(256) void k_ea_reduce(const float* __restrict__ ea,
                                                   float* __restrict__ ea_sum, int E) {
    float s[8];
#pragma unroll
    for (int i = 0; i < 8; i++) s[i] = 0.f;
    for (int e = blockIdx.x * blockDim.x + threadIdx.x; e < E; e += gridDim.x * blockDim.x) {
        const float4* p = (const float4*)(ea + (size_t)e * 8);
        float4 a = p[0], b = p[1];
        s[0] += a.x; s[1] += a.y; s[2] += a.z; s[3] += a.w;
        s[4] += b.x; s[5] += b.y; s[6] += b.z; s[7] += b.w;
    }
#pragma unroll
    for (int o = 32; o; o >>= 1)
#pragma unroll
        for (int i = 0; i < 8; i++) s[i] += __shfl_xor(s[i], o, 64);
    __shared__ float sh[4][8];
    int lane = threadIdx.x & 63, w = threadIdx.x >> 6;
    if (lane == 0)
#pragma unroll
        for (int i = 0; i < 8; i++) sh[w][i] = s[i];
    __syncthreads();
    if (threadIdx.x < 8) {
        float v = sh[0][threadIdx.x] + sh[1][threadIdx.x] + sh[2][threadIdx.x] + sh[3][threadIdx.x];
        atomicAdd(ea_sum + threadIdx.x, v);
    }
}

// ---------- CSR build: count / scan / scatter ----------
__global__ __launch_bounds__(256) void k_count(const int* __restrict__ ei, int* __restrict__ counts,
                                               int E, int N) {
    int e = blockIdx.x * blockDim.x + threadIdx.x;
    if (e >= E + N) return;
    int d = (e < E) ? ei[E + e] : (e - E);
    atomicAdd(counts + d, 1);
}

__global__ __launch_bounds__(1024) void k_scan(const int* __restrict__ counts, int* __restrict__ off,
                                               int* __restrict__ cursor, int N) {
    __shared__ int buf[1024];
    int t = threadIdx.x;
    int carry = 0;
    if (t == 0) off[0] = 0;
    for (int base = 0; base < N; base += 1024) {
        int i = base + t;
        int v = (i < N) ? counts[i] : 0;
        buf[t] = v;
        __syncthreads();
        for (int o = 1; o < 1024; o <<= 1) {
            int add = (t >= o) ? buf[t - o] : 0;
            __syncthreads();
            buf[t] += add;
            __syncthreads();
        }
        int incl = buf[t] + carry;
        if (i < N) { off[i + 1] = incl; cursor[i] = incl - v; }
        int tot = buf[1023];
        __syncthreads();
        carry += tot;
    }
}

__global__ __launch_bounds__(256) void k_scatter(const int* __restrict__ ei, int* __restrict__ cursor,
                                                 int* __restrict__ csr_src, int* __restrict__ csr_eid,
                                                 int E, int N) {
    int e = blockIdx.x * blockDim.x + threadIdx.x;
    if (e >= E + N) return;
    int s, d;
    if (e < E) { s = ei[e]; d = ei[E + e]; }
    else { s = d = e - E; }
    int pos = atomicAdd(cursor + d, 1);
    csr_src[pos] = s;
    csr_eid[pos] = e;
}

// ---------- node transform 1: xl1 = x@Wl1+bl1, xr1 = x@Wr1+br1 ----------
__global__ __launch_bounds__(256) void k_ntrans1(const float* __restrict__ x,
                                                 const float* __restrict__ Wl, const float* __restrict__ bl,
                                                 const float* __restrict__ Wr, const float* __restrict__ br,
                                                 float* __restrict__ xl1, float* __restrict__ xr1, int N) {
    __shared__ float swl[16 * 256];
    __shared__ float swr[16 * 256];
    __shared__ float sx[32 * 16];
    int t = threadIdx.x;
#pragma unroll
    for (int k = 0; k < 16; k++) { swl[k * 256 + t] = Wl[k * 256 + t]; swr[k * 256 + t] = Wr[k * 256 + t]; }
    int n0 = blockIdx.x * 32;
    for (int i = t; i < 32 * 16; i += 256) {
        int n = n0 + (i >> 4);
        sx[i] = (n < N) ? x[(size_t)n * 16 + (i & 15)] : 0.f;
    }
    __syncthreads();
    float bL = bl[t], bR = br[t];
    for (int ni = 0; ni < 32; ni++) {
        int n = n0 + ni;
        if (n >= N) break;
        float al = bL, ar = bR;
#pragma unroll
        for (int k = 0; k < 16; k++) {
            float xv = sx[ni * 16 + k];
            al += xv * swl[k * 256 + t];
            ar += xv * swr[k * 256 + t];
        }
        xl1[(size_t)n * 256 + t] = al;
        xr1[(size_t)n * 256 + t] = ar;
    }
}

// ---------- fused conv1: per-node attention + aggregation + bn + residual + elu ----------
// One wave per node. Lane owns channels c4..c4+3 (head h = lane>>4).
// Pass 1: logits over incident edges (stored to alpha by CSR position), track per-head max.
// Pass 2: exp, weighted sum of xl1[src], denom. Then normalize + bias + bn + x@Wres + elu.
__global__ __launch_bounds__(256) void k_fagg1(const float* __restrict__ xl1, const float* __restrict__ xr1,
                                               const int* __restrict__ off, const int* __restrict__ csr_src,
                                               const int* __restrict__ csr_eid,
                                               const float* __restrict__ ea, const float* __restrict__ ea_sum,
                                               const float* __restrict__ We1, const float* __restrict__ att1,
                                               const float* __restrict__ bias1,
                                               const float* __restrict__ x, const float* __restrict__ Wres,
                                               const float* __restrict__ g, const float* __restrict__ bb_,
                                               const float* __restrict__ mm_, const float* __restrict__ vv_,
                                               float* __restrict__ alpha, float* __restrict__ h1,
                                               int E, int N) {
    __shared__ float swe[8 * 256];
    __shared__ float swres[16 * 256];
    int t = threadIdx.x;
    for (int i = t; i < 8 * 256; i += 256) swe[i] = We1[i];
    for (int i = t; i < 16 * 256; i += 256) swres[i] = Wres[i];
    __syncthreads();
    int lane = t & 63, w = t >> 6;
    int node = blockIdx.x * 4 + w;
    if (node >= N) return;
    int h = lane >> 4;
    int c4 = lane * 4;
    int beg = off[node], end = off[node + 1];
    float4 xr4 = *(const float4*)(xr1 + (size_t)node * 256 + c4);
    float4 at4 = *(const float4*)(att1 + c4);
    float invE = 1.f / (float)E;
    float eamean[8];
#pragma unroll
    for (int k = 0; k < 8; k++) eamean[k] = ea_sum[k] * invE;
    float mymax = -1e30f;
    for (int i = beg; i < end; i++) {
        int s = csr_src[i], e = csr_eid[i];
        float eav[8];
        if (e < E) {
#pragma unroll
            for (int k = 0; k < 8; k++) eav[k] = ea[(size_t)e * 8 + k];
        } else {
#pragma unroll
            for (int k = 0; k < 8; k++) eav[k] = eamean[k];
        }
        float4 xs = *(const float4*)(xl1 + (size_t)s * 256 + c4);
        float4 ee = make_float4(0.f, 0.f, 0.f, 0.f);
#pragma unroll
        for (int k = 0; k < 8; k++) {
            float a = eav[k];
            float4 wv = *(const float4*)(swe + k * 256 + c4);
            ee.x += a * wv.x; ee.y += a * wv.y; ee.z += a * wv.z; ee.w += a * wv.w;
        }
        float4 v;
        v.x = xs.x + xr4.x + ee.x; v.y = xs.y + xr4.y + ee.y;
        v.z = xs.z + xr4.z + ee.z; v.w = xs.w + xr4.w + ee.w;
        v.x = v.x > 0.f ? v.x : 0.2f * v.x;
        v.y = v.y > 0.f ? v.y : 0.2f * v.y;
        v.z = v.z > 0.f ? v.z : 0.2f * v.z;
        v.w = v.w > 0.f ? v.w : 0.2f * v.w;
        float p = v.x * at4.x + v.y * at4.y + v.z * at4.z + v.w * at4.w;
        p += __shfl_xor(p, 1, 64);
        p += __shfl_xor(p, 2, 64);
        p += __shfl_xor(p, 4, 64);
        p += __shfl_xor(p, 8, 64);
        if ((lane & 15) == 0) alpha[(size_t)i * 4 + h] = p;
        mymax = fmaxf(mymax, p);
    }
    float4 acc = make_float4(0.f, 0.f, 0.f, 0.f);
    float sumw = 0.f;
    for (int i = beg; i < end; i++) {
        int s = csr_src[i];
        float p = alpha[(size_t)i * 4 + h];
        float wgt = expf(p - mymax);
        sumw += wgt;
        float4 xs = *(const float4*)(xl1 + (size_t)s * 256 + c4);
        acc.x += wgt * xs.x; acc.y += wgt * xs.y; acc.z += wgt * xs.z; acc.w += wgt * xs.w;
    }
    float inv = 1.f / (sumw + 1e-16f);
    // residual x@Wres
    float4 r = make_float4(0.f, 0.f, 0.f, 0.f);
    const float* xp = x + (size_t)node * 16;
#pragma unroll
    for (int k = 0; k < 16; k++) {
        float xv = xp[k];
        float4 wv = *(const float4*)(swres + k * 256 + c4);
        r.x += xv * wv.x; r.y += xv * wv.y; r.z += xv * wv.z; r.w += xv * wv.w;
    }
    float4 bi = *(const float4*)(bias1 + c4);
    float4 g4 = *(const float4*)(g + c4);
    float4 b4 = *(const float4*)(bb_ + c4);
    float4 m4 = *(const float4*)(mm_ + c4);
    float4 v4 = *(const float4*)(vv_ + c4);
    float4 o;
    o.x = acc.x * inv + bi.x; o.y = acc.y * inv + bi.y;
    o.z = acc.z * inv + bi.z; o.w = acc.w * inv + bi.w;
    o.x = (o.x - m4.x) * rsqrtf(v4.x + 1e-5f) * g4.x + b4.x + r.x;
    o.y = (o.y - m4.y) * rsqrtf(v4.y + 1e-5f) * g4.y + b4.y + r.y;
    o.z = (o.z - m4.z) * rsqrtf(v4.z + 1e-5f) * g4.z + b4.z + r.z;
    o.w = (o.w - m4.w) * rsqrtf(v4.w + 1e-5f) * g4.w + b4.w + r.w;
    o.x = elu_f(o.x); o.y = elu_f(o.y); o.z = elu_f(o.z); o.w = elu_f(o.w);
    *(float4*)(h1 + (size_t)node * 256 + c4) = o;
}

// ---------- xl2 = h1@Wl2+bl2, xr2 = h1@Wr2+br2 (register-tiled) ----------
__global__ __launch_bounds__(256) void k_xlr2(const float* __restrict__ h1,
                                              const float* __restrict__ Wl2, const float* __restrict__ bl2,
                                              const float* __restrict__ Wr2, const float* __restrict__ br2,
                                              float* __restrict__ xl2, float* __restrict__ xr2, int N) {
    __shared__ float sh[32][32];    // [kk][node]
    __shared__ float sw[32][128];   // [kk][col]
    int t = threadIdx.x;
    int tr = t >> 5, tc = t & 31;
    int n0 = blockIdx.x * 32;
    float acc[4][4];
#pragma unroll
    for (int i = 0; i < 4; i++)
#pragma unroll
        for (int j = 0; j < 4; j++) acc[i][j] = 0.f;
    for (int k0 = 0; k0 < 256; k0 += 32) {
        {
            int n = t >> 3, kk0 = (t & 7) * 4;
            int gn = n0 + n;
            float4 hv = make_float4(0.f, 0.f, 0.f, 0.f);
            if (gn < N) hv = *(const float4*)(h1 + (size_t)gn * 256 + k0 + kk0);
            sh[kk0 + 0][n] = hv.x; sh[kk0 + 1][n] = hv.y; sh[kk0 + 2][n] = hv.z; sh[kk0 + 3][n] = hv.w;
        }
        for (int i = t; i < 32 * 128; i += 256) {
            int kk = i >> 7, c = i & 127;
            sw[kk][c] = (c < 64) ? Wl2[(size_t)(k0 + kk) * 64 + c] : Wr2[(size_t)(k0 + kk) * 64 + (c - 64)];
        }
        __syncthreads();
#pragma unroll
        for (int kk = 0; kk < 32; kk++) {
            float4 hv = *(const float4*)&sh[kk][tr * 4];
            float4 wv = *(const float4*)&sw[kk][tc * 4];
            float hh[4] = { hv.x, hv.y, hv.z, hv.w };
            float wwv[4] = { wv.x, wv.y, wv.z, wv.w };
#pragma unroll
            for (int i = 0; i < 4; i++)
#pragma unroll
                for (int j = 0; j < 4; j++) acc[i][j] += hh[i] * wwv[j];
        }
        __syncthreads();
    }
#pragma unroll
    for (int i = 0; i < 4; i++) {
        int gn = n0 + tr * 4 + i;
        if (gn >= N) continue;
#pragma unroll
        for (int j = 0; j < 4; j++) {
            int c = tc * 4 + j;
            float vv = acc[i][j];
            if (c < 64) xl2[(size_t)gn * 64 + c] = vv + bl2[c];
            else        xr2[(size_t)gn * 64 + (c - 64)] = vv + br2[c - 64];
        }
    }
}

// ---------- fused conv2: per-node attention + aggregation + bn + elu ----------
// One wave per node, lane owns channel c=lane.
__global__ __launch_bounds__(256) void k_fagg2(const float* __restrict__ xl2, const float* __restrict__ xr2,
                                               const int* __restrict__ off, const int* __restrict__ csr_src,
                                               const int* __restrict__ csr_eid,
                                               const float* __restrict__ ea, const float* __restrict__ ea_sum,
                                               const float* __restrict__ We2, const float* __restrict__ att2,
                                               const float* __restrict__ bias2,
                                               const float* __restrict__ g, const float* __restrict__ bb_,
                                               const float* __restrict__ mm_, const float* __restrict__ vv_,
                                               float* __restrict__ alpha, float* __restrict__ h2,
                                               int E, int N) {
    __shared__ float swe[8 * 64];
    int t = threadIdx.x;
    if (t < 512) swe[t] = We2[t];
    __syncthreads();
    int lane = t & 63, w = t >> 6;
    int node = blockIdx.x * 4 + w;
    if (node >= N) return;
    int beg = off[node], end = off[node + 1];
    float xr = xr2[(size_t)node * 64 + lane];
    float at = att2[lane];
    float invE = 1.f / (float)E;
    float eamean[8];
#pragma unroll
    for (int k = 0; k < 8; k++) eamean[k] = ea_sum[k] * invE;
    float mymax = -1e30f;
    for (int i = beg; i < end; i++) {
        int s = csr_src[i], e = csr_eid[i];
        float eav[8];
        if (e < E) {
#pragma unroll
            for (int k = 0; k < 8; k++) eav[k] = ea[(size_t)e * 8 + k];
        } else {
#pragma unroll
            for (int k = 0; k < 8; k++) eav[k] = eamean[k];
        }
        float v = xl2[(size_t)s * 64 + lane] + xr;
#pragma unroll
        for (int k = 0; k < 8; k++) v += eav[k] * swe[k * 64 + lane];
        v = v > 0.f ? v : 0.2f * v;
        float p = v * at;
#pragma unroll
        for (int o = 32; o; o >>= 1) p += __shfl_xor(p, o, 64);
        if (lane == 0) alpha[i] = p;
        mymax = fmaxf(mymax, p);
    }
    float acc = 0.f, sumw = 0.f;
    for (int i = beg; i < end; i++) {
        int s = csr_src[i];
        float p = alpha[i];
        float wgt = expf(p - mymax);
        sumw += wgt;
        acc += wgt * xl2[(size_t)s * 64 + lane];
    }
    float val = acc / (sumw + 1e-16f) + bias2[lane];
    val = (val - mm_[lane]) * rsqrtf(vv_[lane] + 1e-5f) * g[lane] + bb_[lane];
    h2[(size_t)node * 64 + lane] = elu_f(val);
}

// ---------- edge MLP head: tiled GEMM, 64 edges per block ----------
__global__ __launch_bounds__(256) void k_mlp(const float* __restrict__ h2, const int* __restrict__ ei,
                                             const float* __restrict__ ea,
                                             const float* __restrict__ Wm1, const float* __restrict__ bm1,
                                             const float* __restrict__ Wm2, const float* __restrict__ bm2,
                                             const float* __restrict__ Wm3, const float* __restrict__ bm3,
                                             float* __restrict__ out, int E) {
    __shared__ float sw1[136 * 64];
    __shared__ float sw2[64 * 32];
    __shared__ float sw3[32];
    __shared__ int sre[64], sce[64];
    __shared__ float sa[64 * 140];
    int t = threadIdx.x;
    for (int i = t; i < 136 * 64; i += 256) sw1[i] = Wm1[i];
    for (int i = t; i < 64 * 32; i += 256) sw2[i] = Wm2[i];
    if (t < 32) sw3[t] = Wm3[t];
    int e0 = blockIdx.x * 64;
    if (t < 64) {
        int e = e0 + t;
        if (e < E) { sre[t] = ei[e]; sce[t] = ei[E + e]; }
        else { sre[t] = 0; sce[t] = 0; }
    }
    __syncthreads();
    for (int i = t; i < 64 * 34; i += 256) {
        int el = i / 34, q = i - el * 34;
        float4 v;
        if (q < 16)      v = *(const float4*)(h2 + (size_t)sre[el] * 64 + q * 4);
        else if (q < 32) v = *(const float4*)(h2 + (size_t)sce[el] * 64 + (q - 16) * 4);
        else             v = *(const float4*)(ea + (size_t)(e0 + el) * 8 + (q - 32) * 4);
        *(float4*)(sa + el * 140 + q * 4) = v;
    }
    __syncthreads();
    int tr = t >> 4, tc = t & 15;
    float acc[4][4];
#pragma unroll
    for (int j = 0; j < 4; j++) {
        float bv = bm1[tc * 4 + j];
#pragma unroll
        for (int i = 0; i < 4; i++) acc[i][j] = bv;
    }
    for (int k = 0; k < 136; k++) {
        float4 bv = *(const float4*)(sw1 + k * 64 + tc * 4);
        float a0 = sa[(tr * 4 + 0) * 140 + k];
        float a1 = sa[(tr * 4 + 1) * 140 + k];
        float a2 = sa[(tr * 4 + 2) * 140 + k];
        float a3 = sa[(tr * 4 + 3) * 140 + k];
        acc[0][0] += a0 * bv.x; acc[0][1] += a0 * bv.y; acc[0][2] += a0 * bv.z; acc[0][3] += a0 * bv.w;
        acc[1][0] += a1 * bv.x; acc[1][1] += a1 * bv.y; acc[1][2] += a1 * bv.z; acc[1][3] += a1 * bv.w;
        acc[2][0] += a2 * bv.x; acc[2][1] += a2 * bv.y; acc[2][2] += a2 * bv.z; acc[2][3] += a2 * bv.w;
        acc[3][0] += a3 * bv.x; acc[3][1] += a3 * bv.y; acc[3][2] += a3 * bv.z; acc[3][3] += a3 * bv.w;
    }
    __syncthreads();
#pragma unroll
    for (int i = 0; i < 4; i++) {
        float4 z;
        z.x = gelu_f(acc[i][0]); z.y = gelu_f(acc[i][1]);
        z.z = gelu_f(acc[i][2]); z.w = gelu_f(acc[i][3]);
        *(float4*)(sa + (tr * 4 + i) * 140 + tc * 4) = z;
    }
    __syncthreads();
    float acc2[4][2];
#pragma unroll
    for (int j = 0; j < 2; j++) {
        float bv = bm2[tc * 2 + j];
#pragma unroll
        for (int i = 0; i < 4; i++) acc2[i][j] = bv;
    }
    for (int k = 0; k < 64; k++) {
        float2 bv = *(const float2*)(sw2 + k * 32 + tc * 2);
        float a0 = sa[(tr * 4 + 0) * 140 + k];
        float a1 = sa[(tr * 4 + 1) * 140 + k];
        float a2 = sa[(tr * 4 + 2) * 140 + k];
        float a3 = sa[(tr * 4 + 3) * 140 + k];
        acc2[0][0] += a0 * bv.x; acc2[0][1] += a0 * bv.y;
        acc2[1][0] += a1 * bv.x; acc2[1][1] += a1 * bv.y;
        acc2[2][0] += a2 * bv.x; acc2[2][1] += a2 * bv.y;
        acc2[3][0] += a3 * bv.x; acc2[3][1] += a3 * bv.y;
    }
    __syncthreads();
#pragma unroll
    for (int i = 0; i < 4; i++)
#pragma unroll
        for (int j = 0; j < 2; j++)
            sa[(tr * 4 + i) * 140 + 96 + tc * 2 + j] = gelu_f(acc2[i][j]);
    __syncthreads();
    if (t < 64) {
        float s = bm3[0];
#pragma unroll
        for (int k = 0; k < 32; k++) s += sa[t * 140 + 96 + k] * sw3[k];
        int e = e0 + t;
        if (e < E) out[e] = 1.f / (1.f + expf(-s));
    }
}

extern "C" void kernel_launch(void* const* d_in, const int* in_sizes, int n_in,
                              void* d_out, int out_size, void* d_ws, size_t ws_size,
                              hipStream_t stream) {
    const float* x    = (const float*)d_in[0];
    const int*   ei   = (const int*)d_in[1];
    const float* ea   = (const float*)d_in[2];
    const float* Wl1  = (const float*)d_in[3];
    const float* bl1  = (const float*)d_in[4];
    const float* Wr1  = (const float*)d_in[5];
    const float* br1  = (const float*)d_in[6];
    const float* We1  = (const float*)d_in[7];
    const float* att1 = (const float*)d_in[8];
    const float* bias1= (const float*)d_in[9];
    const float* Wl2  = (const float*)d_in[10];
    const float* bl2  = (const float*)d_in[11];
    const float* Wr2  = (const float*)d_in[12];
    const float* br2  = (const float*)d_in[13];
    const float* We2  = (const float*)d_in[14];
    const float* att2 = (const float*)d_in[15];
    const float* bias2= (const float*)d_in[16];
    const float* bn1g = (const float*)d_in[17];
    const float* bn1b = (const float*)d_in[18];
    const float* bn1m = (const float*)d_in[19];
    const float* bn1v = (const float*)d_in[20];
    const float* bn2g = (const float*)d_in[21];
    const float* bn2b = (const float*)d_in[22];
    const float* bn2m = (const float*)d_in[23];
    const float* bn2v = (const float*)d_in[24];
    const float* Wres = (const float*)d_in[25];
    const float* Wm1  = (const float*)d_in[26];
    const float* bm1  = (const float*)d_in[27];
    const float* Wm2  = (const float*)d_in[28];
    const float* bm2  = (const float*)d_in[29];
    const float* Wm3  = (const float*)d_in[30];
    const float* bm3  = (const float*)d_in[31];
    float* out = (float*)d_out;
    float* ws = (float*)d_ws;

    const int N = NN, E = EE, Etot = ETOT;

    // workspace layout (floats)
    float* ea_sum   = ws;                                   // 16
    int*   counts   = (int*)(ws + 16);                      // N
    int*   off      = (int*)(ws + 16 + (size_t)N);          // N+16
    int*   cursor   = (int*)(ws + 32 + (size_t)2 * N);      // N
    int*   csr_src  = (int*)(ws + 32 + (size_t)3 * N);      // Etot
    int*   csr_eid  = (int*)(ws + 32 + (size_t)3 * N + Etot); // Etot
    float* alpha    = ws + 32 + (size_t)3 * N + (size_t)2 * Etot;  // 4*Etot
    float* A        = alpha + (size_t)4 * Etot;             // 256N
    float* B        = A + (size_t)256 * N;                  // 256N

    float* xl1 = A;
    float* xr1 = B;
    float* h1  = B;                    // overwrites xr1 in-place (safe: row read before write)
    float* xl2 = A;                    // reuses xl1 (dead after k_fagg1)
    float* xr2 = A + (size_t)64 * N;
    float* h2  = A + (size_t)128 * N;

    hipMemsetAsync(ea_sum, 0, 16 * sizeof(float), stream);
    hipMemsetAsync(counts, 0, (size_t)N * sizeof(int), stream);

    k_ea_reduce<<<256, 256, 0, stream>>>(ea, ea_sum, E);
    k_count<<<(Etot + 255) / 256, 256, 0, stream>>>(ei, counts, E, N);
    k_scan<<<1, 1024, 0, stream>>>(counts, off, cursor, N);
    k_scatter<<<(Etot + 255) / 256, 256, 0, stream>>>(ei, cursor, csr_src, csr_eid, E, N);
    k_ntrans1<<<(N + 31) / 32, 256, 0, stream>>>(x, Wl1, bl1, Wr1, br1, xl1, xr1, N);
    k_fagg1<<<(N + 3) / 4, 256, 0, stream>>>(xl1, xr1, off, csr_src, csr_eid, ea, ea_sum,
                                             We1, att1, bias1, x, Wres,
                                             bn1g, bn1b, bn1m, bn1v, alpha, h1, E, N);
    k_xlr2<<<(N + 31) / 32, 256, 0, stream>>>(h1, Wl2, bl2, Wr2, br2, xl2, xr2, N);
    k_fagg2<<<(N + 3) / 4, 256, 0, stream>>>(xl2, xr2, off, csr_src, csr_eid, ea, ea_sum,
                                             We2, att2, bias2,
                                             bn2g, bn2b, bn2m, bn2v, alpha, h2, E, N);
    k_node2_dummy: ;
    k_mlp<<<(E + 63) / 64, 256, 0, stream>>>(h2, ei, ea, Wm1, bm1, Wm2, bm2, Wm3, bm3, out, E);
}

// Round 4
// 868.834 us; speedup vs baseline: 1.6187x; 1.0933x over previous
//
#include <hip/hip_runtime.h>
#include <hip/hip_bf16.h>
#include <math.h>

#define NN 50000
#define EE 400000
#define ETOT (NN + EE)

// ---------- helpers ----------
__device__ __forceinline__ float gelu_f(float x) {
    return 0.5f * x * (1.f + erff(x * 0.7071067811865476f));
}
__device__ __forceinline__ float elu_f(float x) {
    return x > 0.f ? x : expm1f(x);
}

// ---------- ea mean (sum) ----------
__global__ __launch_bounds__(256) void k_ea_reduce(const float* __restrict__ ea,
                                                   float* __restrict__ ea_sum, int E) {
    float s[8];
#pragma unroll
    for (int i = 0; i < 8; i++) s[i] = 0.f;
    for (int e = blockIdx.x * blockDim.x + threadIdx.x; e < E; e += gridDim.x * blockDim.x) {
        const float4* p = (const float4*)(ea + (size_t)e * 8);
        float4 a = p[0], b = p[1];
        s[0] += a.x; s[1] += a.y; s[2] += a.z; s[3] += a.w;
        s[4] += b.x; s[5] += b.y; s[6] += b.z; s[7] += b.w;
    }
#pragma unroll
    for (int o = 32; o; o >>= 1)
#pragma unroll
        for (int i = 0; i < 8; i++) s[i] += __shfl_xor(s[i], o, 64);
    __shared__ float sh[4][8];
    int lane = threadIdx.x & 63, w = threadIdx.x >> 6;
    if (lane == 0)
#pragma unroll
        for (int i = 0; i < 8; i++) sh[w][i] = s[i];
    __syncthreads();
    if (threadIdx.x < 8) {
        float v = sh[0][threadIdx.x] + sh[1][threadIdx.x] + sh[2][threadIdx.x] + sh[3][threadIdx.x];
        atomicAdd(ea_sum + threadIdx.x, v);
    }
}

// ---------- CSR build: count / scan / scatter ----------
__global__ __launch_bounds__(256) void k_count(const int* __restrict__ ei, int* __restrict__ counts,
                                               int E, int N) {
    int e = blockIdx.x * blockDim.x + threadIdx.x;
    if (e >= E + N) return;
    int d = (e < E) ? ei[E + e] : (e - E);
    atomicAdd(counts + d, 1);
}

__global__ __launch_bounds__(1024) void k_scan(const int* __restrict__ counts, int* __restrict__ off,
                                               int* __restrict__ cursor, int N) {
    __shared__ int buf[1024];
    int t = threadIdx.x;
    int carry = 0;
    if (t == 0) off[0] = 0;
    for (int base = 0; base < N; base += 1024) {
        int i = base + t;
        int v = (i < N) ? counts[i] : 0;
        buf[t] = v;
        __syncthreads();
        for (int o = 1; o < 1024; o <<= 1) {
            int add = (t >= o) ? buf[t - o] : 0;
            __syncthreads();
            buf[t] += add;
            __syncthreads();
        }
        int incl = buf[t] + carry;
        if (i < N) { off[i + 1] = incl; cursor[i] = incl - v; }
        int tot = buf[1023];
        __syncthreads();
        carry += tot;
    }
}

__global__ __launch_bounds__(256) void k_scatter(const int* __restrict__ ei, int* __restrict__ cursor,
                                                 int* __restrict__ csr_src, int* __restrict__ csr_eid,
                                                 int E, int N) {
    int e = blockIdx.x * blockDim.x + threadIdx.x;
    if (e >= E + N) return;
    int s, d;
    if (e < E) { s = ei[e]; d = ei[E + e]; }
    else { s = d = e - E; }
    int pos = atomicAdd(cursor + d, 1);
    csr_src[pos] = s;
    csr_eid[pos] = e;
}

// ---------- node transform 1: xl1 = x@Wl1+bl1, xr1 = x@Wr1+br1 ----------
__global__ __launch_bounds__(256) void k_ntrans1(const float* __restrict__ x,
                                                 const float* __restrict__ Wl, const float* __restrict__ bl,
                                                 const float* __restrict__ Wr, const float* __restrict__ br,
                                                 float* __restrict__ xl1, float* __restrict__ xr1, int N) {
    __shared__ float swl[16 * 256];
    __shared__ float swr[16 * 256];
    __shared__ float sx[32 * 16];
    int t = threadIdx.x;
#pragma unroll
    for (int k = 0; k < 16; k++) { swl[k * 256 + t] = Wl[k * 256 + t]; swr[k * 256 + t] = Wr[k * 256 + t]; }
    int n0 = blockIdx.x * 32;
    for (int i = t; i < 32 * 16; i += 256) {
        int n = n0 + (i >> 4);
        sx[i] = (n < N) ? x[(size_t)n * 16 + (i & 15)] : 0.f;
    }
    __syncthreads();
    float bL = bl[t], bR = br[t];
    for (int ni = 0; ni < 32; ni++) {
        int n = n0 + ni;
        if (n >= N) break;
        float al = bL, ar = bR;
#pragma unroll
        for (int k = 0; k < 16; k++) {
            float xv = sx[ni * 16 + k];
            al += xv * swl[k * 256 + t];
            ar += xv * swr[k * 256 + t];
        }
        xl1[(size_t)n * 256 + t] = al;
        xr1[(size_t)n * 256 + t] = ar;
    }
}

// ---------- fused conv1 (online softmax, single gather pass) ----------
// One wave per node. Lane owns channels c4..c4+3 (head h = lane>>4).
// Per edge: logit p (16-lane reduce), online-rescaled weighted accumulation of xl1[src].
// Epilogue: normalize + bias + bn + x@Wres + elu.
__global__ __launch_bounds__(256) void k_fagg1(const float* __restrict__ xl1, const float* __restrict__ xr1,
                                               const int* __restrict__ off, const int* __restrict__ csr_src,
                                               const int* __restrict__ csr_eid,
                                               const float* __restrict__ ea, const float* __restrict__ ea_sum,
                                               const float* __restrict__ We1, const float* __restrict__ att1,
                                               const float* __restrict__ bias1,
                                               const float* __restrict__ x, const float* __restrict__ Wres,
                                               const float* __restrict__ g, const float* __restrict__ bb_,
                                               const float* __restrict__ mm_, const float* __restrict__ vv_,
                                               float* __restrict__ h1,
                                               int E, int N) {
    __shared__ float swe[8 * 256];
    __shared__ float swres[16 * 256];
    int t = threadIdx.x;
    for (int i = t; i < 8 * 256; i += 256) swe[i] = We1[i];
    for (int i = t; i < 16 * 256; i += 256) swres[i] = Wres[i];
    __syncthreads();
    int lane = t & 63, w = t >> 6;
    int node = blockIdx.x * 4 + w;
    if (node >= N) return;
    int c4 = lane * 4;
    int beg = off[node], end = off[node + 1];
    float4 xr4 = *(const float4*)(xr1 + (size_t)node * 256 + c4);
    float4 at4 = *(const float4*)(att1 + c4);
    float invE = 1.f / (float)E;
    float eamean[8];
#pragma unroll
    for (int k = 0; k < 8; k++) eamean[k] = ea_sum[k] * invE;

    float m = -1e30f, sumw = 0.f;
    float4 acc = make_float4(0.f, 0.f, 0.f, 0.f);

    // prefetch first edge (every node has >=1 edge: its self-loop)
    int s = csr_src[beg], e = csr_eid[beg];
    float4 xs = *(const float4*)(xl1 + (size_t)s * 256 + c4);

    for (int i = beg; i < end; i++) {
        // prefetch next edge
        int sn = 0, en = 0;
        float4 xsn = make_float4(0.f, 0.f, 0.f, 0.f);
        if (i + 1 < end) {
            sn = csr_src[i + 1]; en = csr_eid[i + 1];
            xsn = *(const float4*)(xl1 + (size_t)sn * 256 + c4);
        }
        float eav[8];
        if (e < E) {
#pragma unroll
            for (int k = 0; k < 8; k++) eav[k] = ea[(size_t)e * 8 + k];
        } else {
#pragma unroll
            for (int k = 0; k < 8; k++) eav[k] = eamean[k];
        }
        float4 ee = make_float4(0.f, 0.f, 0.f, 0.f);
#pragma unroll
        for (int k = 0; k < 8; k++) {
            float a = eav[k];
            float4 wv = *(const float4*)(swe + k * 256 + c4);
            ee.x += a * wv.x; ee.y += a * wv.y; ee.z += a * wv.z; ee.w += a * wv.w;
        }
        float4 v;
        v.x = xs.x + xr4.x + ee.x; v.y = xs.y + xr4.y + ee.y;
        v.z = xs.z + xr4.z + ee.z; v.w = xs.w + xr4.w + ee.w;
        v.x = v.x > 0.f ? v.x : 0.2f * v.x;
        v.y = v.y > 0.f ? v.y : 0.2f * v.y;
        v.z = v.z > 0.f ? v.z : 0.2f * v.z;
        v.w = v.w > 0.f ? v.w : 0.2f * v.w;
        float p = v.x * at4.x + v.y * at4.y + v.z * at4.z + v.w * at4.w;
        p += __shfl_xor(p, 1, 64);
        p += __shfl_xor(p, 2, 64);
        p += __shfl_xor(p, 4, 64);
        p += __shfl_xor(p, 8, 64);
        // online softmax update (branchless)
        float mn = fmaxf(m, p);
        float sc = expf(m - mn);
        float wgt = expf(p - mn);
        acc.x = acc.x * sc + wgt * xs.x;
        acc.y = acc.y * sc + wgt * xs.y;
        acc.z = acc.z * sc + wgt * xs.z;
        acc.w = acc.w * sc + wgt * xs.w;
        sumw = sumw * sc + wgt;
        m = mn;
        s = sn; e = en; xs = xsn;
    }
    float inv = 1.f / (sumw + 1e-16f);
    // residual x@Wres
    float4 r = make_float4(0.f, 0.f, 0.f, 0.f);
    const float* xp = x + (size_t)node * 16;
#pragma unroll
    for (int k = 0; k < 16; k++) {
        float xv = xp[k];
        float4 wv = *(const float4*)(swres + k * 256 + c4);
        r.x += xv * wv.x; r.y += xv * wv.y; r.z += xv * wv.z; r.w += xv * wv.w;
    }
    float4 bi = *(const float4*)(bias1 + c4);
    float4 g4 = *(const float4*)(g + c4);
    float4 b4 = *(const float4*)(bb_ + c4);
    float4 m4 = *(const float4*)(mm_ + c4);
    float4 v4 = *(const float4*)(vv_ + c4);
    float4 o;
    o.x = acc.x * inv + bi.x; o.y = acc.y * inv + bi.y;
    o.z = acc.z * inv + bi.z; o.w = acc.w * inv + bi.w;
    o.x = (o.x - m4.x) * rsqrtf(v4.x + 1e-5f) * g4.x + b4.x + r.x;
    o.y = (o.y - m4.y) * rsqrtf(v4.y + 1e-5f) * g4.y + b4.y + r.y;
    o.z = (o.z - m4.z) * rsqrtf(v4.z + 1e-5f) * g4.z + b4.z + r.z;
    o.w = (o.w - m4.w) * rsqrtf(v4.w + 1e-5f) * g4.w + b4.w + r.w;
    o.x = elu_f(o.x); o.y = elu_f(o.y); o.z = elu_f(o.z); o.w = elu_f(o.w);
    *(float4*)(h1 + (size_t)node * 256 + c4) = o;
}

// ---------- xl2 = h1@Wl2+bl2, xr2 = h1@Wr2+br2 (register-tiled) ----------
__global__ __launch_bounds__(256) void k_xlr2(const float* __restrict__ h1,
                                              const float* __restrict__ Wl2, const float* __restrict__ bl2,
                                              const float* __restrict__ Wr2, const float* __restrict__ br2,
                                              float* __restrict__ xl2, float* __restrict__ xr2, int N) {
    __shared__ float sh[32][32];    // [kk][node]
    __shared__ float sw[32][128];   // [kk][col]
    int t = threadIdx.x;
    int tr = t >> 5, tc = t & 31;
    int n0 = blockIdx.x * 32;
    float acc[4][4];
#pragma unroll
    for (int i = 0; i < 4; i++)
#pragma unroll
        for (int j = 0; j < 4; j++) acc[i][j] = 0.f;
    for (int k0 = 0; k0 < 256; k0 += 32) {
        {
            int n = t >> 3, kk0 = (t & 7) * 4;
            int gn = n0 + n;
            float4 hv = make_float4(0.f, 0.f, 0.f, 0.f);
            if (gn < N) hv = *(const float4*)(h1 + (size_t)gn * 256 + k0 + kk0);
            sh[kk0 + 0][n] = hv.x; sh[kk0 + 1][n] = hv.y; sh[kk0 + 2][n] = hv.z; sh[kk0 + 3][n] = hv.w;
        }
        for (int i = t; i < 32 * 128; i += 256) {
            int kk = i >> 7, c = i & 127;
            sw[kk][c] = (c < 64) ? Wl2[(size_t)(k0 + kk) * 64 + c] : Wr2[(size_t)(k0 + kk) * 64 + (c - 64)];
        }
        __syncthreads();
#pragma unroll
        for (int kk = 0; kk < 32; kk++) {
            float4 hv = *(const float4*)&sh[kk][tr * 4];
            float4 wv = *(const float4*)&sw[kk][tc * 4];
            float hh[4] = { hv.x, hv.y, hv.z, hv.w };
            float wwv[4] = { wv.x, wv.y, wv.z, wv.w };
#pragma unroll
            for (int i = 0; i < 4; i++)
#pragma unroll
                for (int j = 0; j < 4; j++) acc[i][j] += hh[i] * wwv[j];
        }
        __syncthreads();
    }
#pragma unroll
    for (int i = 0; i < 4; i++) {
        int gn = n0 + tr * 4 + i;
        if (gn >= N) continue;
#pragma unroll
        for (int j = 0; j < 4; j++) {
            int c = tc * 4 + j;
            float vv = acc[i][j];
            if (c < 64) xl2[(size_t)gn * 64 + c] = vv + bl2[c];
            else        xr2[(size_t)gn * 64 + (c - 64)] = vv + br2[c - 64];
        }
    }
}

// ---------- fused conv2 (online softmax, single gather pass) ----------
__global__ __launch_bounds__(256) void k_fagg2(const float* __restrict__ xl2, const float* __restrict__ xr2,
                                               const int* __restrict__ off, const int* __restrict__ csr_src,
                                               const int* __restrict__ csr_eid,
                                               const float* __restrict__ ea, const float* __restrict__ ea_sum,
                                               const float* __restrict__ We2, const float* __restrict__ att2,
                                               const float* __restrict__ bias2,
                                               const float* __restrict__ g, const float* __restrict__ bb_,
                                               const float* __restrict__ mm_, const float* __restrict__ vv_,
                                               float* __restrict__ h2,
                                               int E, int N) {
    __shared__ float swe[8 * 64];
    int t = threadIdx.x;
    if (t < 512) swe[t] = We2[t];
    __syncthreads();
    int lane = t & 63, w = t >> 6;
    int node = blockIdx.x * 4 + w;
    if (node >= N) return;
    int beg = off[node], end = off[node + 1];
    float xr = xr2[(size_t)node * 64 + lane];
    float at = att2[lane];
    float invE = 1.f / (float)E;
    float eamean[8];
#pragma unroll
    for (int k = 0; k < 8; k++) eamean[k] = ea_sum[k] * invE;

    float m = -1e30f, sumw = 0.f, acc = 0.f;
    int s = csr_src[beg], e = csr_eid[beg];
    float xs = xl2[(size_t)s * 64 + lane];

    for (int i = beg; i < end; i++) {
        int sn = 0, en = 0;
        float xsn = 0.f;
        if (i + 1 < end) {
            sn = csr_src[i + 1]; en = csr_eid[i + 1];
            xsn = xl2[(size_t)sn * 64 + lane];
        }
        float eav[8];
        if (e < E) {
#pragma unroll
            for (int k = 0; k < 8; k++) eav[k] = ea[(size_t)e * 8 + k];
        } else {
#pragma unroll
            for (int k = 0; k < 8; k++) eav[k] = eamean[k];
        }
        float v = xs + xr;
#pragma unroll
        for (int k = 0; k < 8; k++) v += eav[k] * swe[k * 64 + lane];
        v = v > 0.f ? v : 0.2f * v;
        float p = v * at;
#pragma unroll
        for (int o = 32; o; o >>= 1) p += __shfl_xor(p, o, 64);
        float mn = fmaxf(m, p);
        float sc = expf(m - mn);
        float wgt = expf(p - mn);
        acc = acc * sc + wgt * xs;
        sumw = sumw * sc + wgt;
        m = mn;
        s = sn; e = en; xs = xsn;
    }
    float val = acc / (sumw + 1e-16f) + bias2[lane];
    val = (val - mm_[lane]) * rsqrtf(vv_[lane] + 1e-5f) * g[lane] + bb_[lane];
    h2[(size_t)node * 64 + lane] = elu_f(val);
}

// ---------- edge MLP head: tiled GEMM, 64 edges per block ----------
__global__ __launch_bounds__(256) void k_mlp(const float* __restrict__ h2, const int* __restrict__ ei,
                                             const float* __restrict__ ea,
                                             const float* __restrict__ Wm1, const float* __restrict__ bm1,
                                             const float* __restrict__ Wm2, const float* __restrict__ bm2,
                                             const float* __restrict__ Wm3, const float* __restrict__ bm3,
                                             float* __restrict__ out, int E) {
    __shared__ float sw1[136 * 64];
    __shared__ float sw2[64 * 32];
    __shared__ float sw3[32];
    __shared__ int sre[64], sce[64];
    __shared__ float sa[64 * 140];
    int t = threadIdx.x;
    for (int i = t; i < 136 * 64; i += 256) sw1[i] = Wm1[i];
    for (int i = t; i < 64 * 32; i += 256) sw2[i] = Wm2[i];
    if (t < 32) sw3[t] = Wm3[t];
    int e0 = blockIdx.x * 64;
    if (t < 64) {
        int e = e0 + t;
        if (e < E) { sre[t] = ei[e]; sce[t] = ei[E + e]; }
        else { sre[t] = 0; sce[t] = 0; }
    }
    __syncthreads();
    for (int i = t; i < 64 * 34; i += 256) {
        int el = i / 34, q = i - el * 34;
        float4 v;
        if (q < 16)      v = *(const float4*)(h2 + (size_t)sre[el] * 64 + q * 4);
        else if (q < 32) v = *(const float4*)(h2 + (size_t)sce[el] * 64 + (q - 16) * 4);
        else             v = *(const float4*)(ea + (size_t)(e0 + el) * 8 + (q - 32) * 4);
        *(float4*)(sa + el * 140 + q * 4) = v;
    }
    __syncthreads();
    int tr = t >> 4, tc = t & 15;
    float acc[4][4];
#pragma unroll
    for (int j = 0; j < 4; j++) {
        float bv = bm1[tc * 4 + j];
#pragma unroll
        for (int i = 0; i < 4; i++) acc[i][j] = bv;
    }
    for (int k = 0; k < 136; k++) {
        float4 bv = *(const float4*)(sw1 + k * 64 + tc * 4);
        float a0 = sa[(tr * 4 + 0) * 140 + k];
        float a1 = sa[(tr * 4 + 1) * 140 + k];
        float a2 = sa[(tr * 4 + 2) * 140 + k];
        float a3 = sa[(tr * 4 + 3) * 140 + k];
        acc[0][0] += a0 * bv.x; acc[0][1] += a0 * bv.y; acc[0][2] += a0 * bv.z; acc[0][3] += a0 * bv.w;
        acc[1][0] += a1 * bv.x; acc[1][1] += a1 * bv.y; acc[1][2] += a1 * bv.z; acc[1][3] += a1 * bv.w;
        acc[2][0] += a2 * bv.x; acc[2][1] += a2 * bv.y; acc[2][2] += a2 * bv.z; acc[2][3] += a2 * bv.w;
        acc[3][0] += a3 * bv.x; acc[3][1] += a3 * bv.y; acc[3][2] += a3 * bv.z; acc[3][3] += a3 * bv.w;
    }
    __syncthreads();
#pragma unroll
    for (int i = 0; i < 4; i++) {
        float4 z;
        z.x = gelu_f(acc[i][0]); z.y = gelu_f(acc[i][1]);
        z.z = gelu_f(acc[i][2]); z.w = gelu_f(acc[i][3]);
        *(float4*)(sa + (tr * 4 + i) * 140 + tc * 4) = z;
    }
    __syncthreads();
    float acc2[4][2];
#pragma unroll
    for (int j = 0; j < 2; j++) {
        float bv = bm2[tc * 2 + j];
#pragma unroll
        for (int i = 0; i < 4; i++) acc2[i][j] = bv;
    }
    for (int k = 0; k < 64; k++) {
        float2 bv = *(const float2*)(sw2 + k * 32 + tc * 2);
        float a0 = sa[(tr * 4 + 0) * 140 + k];
        float a1 = sa[(tr * 4 + 1) * 140 + k];
        float a2 = sa[(tr * 4 + 2) * 140 + k];
        float a3 = sa[(tr * 4 + 3) * 140 + k];
        acc2[0][0] += a0 * bv.x; acc2[0][1] += a0 * bv.y;
        acc2[1][0] += a1 * bv.x; acc2[1][1] += a1 * bv.y;
        acc2[2][0] += a2 * bv.x; acc2[2][1] += a2 * bv.y;
        acc2[3][0] += a3 * bv.x; acc2[3][1] += a3 * bv.y;
    }
    __syncthreads();
#pragma unroll
    for (int i = 0; i < 4; i++)
#pragma unroll
        for (int j = 0; j < 2; j++)
            sa[(tr * 4 + i) * 140 + 96 + tc * 2 + j] = gelu_f(acc2[i][j]);
    __syncthreads();
    if (t < 64) {
        float s = bm3[0];
#pragma unroll
        for (int k = 0; k < 32; k++) s += sa[t * 140 + 96 + k] * sw3[k];
        int e = e0 + t;
        if (e < E) out[e] = 1.f / (1.f + expf(-s));
    }
}

extern "C" void kernel_launch(void* const* d_in, const int* in_sizes, int n_in,
                              void* d_out, int out_size, void* d_ws, size_t ws_size,
                              hipStream_t stream) {
    const float* x    = (const float*)d_in[0];
    const int*   ei   = (const int*)d_in[1];
    const float* ea   = (const float*)d_in[2];
    const float* Wl1  = (const float*)d_in[3];
    const float* bl1  = (const float*)d_in[4];
    const float* Wr1  = (const float*)d_in[5];
    const float* br1  = (const float*)d_in[6];
    const float* We1  = (const float*)d_in[7];
    const float* att1 = (const float*)d_in[8];
    const float* bias1= (const float*)d_in[9];
    const float* Wl2  = (const float*)d_in[10];
    const float* bl2  = (const float*)d_in[11];
    const float* Wr2  = (const float*)d_in[12];
    const float* br2  = (const float*)d_in[13];
    const float* We2  = (const float*)d_in[14];
    const float* att2 = (const float*)d_in[15];
    const float* bias2= (const float*)d_in[16];
    const float* bn1g = (const float*)d_in[17];
    const float* bn1b = (const float*)d_in[18];
    const float* bn1m = (const float*)d_in[19];
    const float* bn1v = (const float*)d_in[20];
    const float* bn2g = (const float*)d_in[21];
    const float* bn2b = (const float*)d_in[22];
    const float* bn2m = (const float*)d_in[23];
    const float* bn2v = (const float*)d_in[24];
    const float* Wres = (const float*)d_in[25];
    const float* Wm1  = (const float*)d_in[26];
    const float* bm1  = (const float*)d_in[27];
    const float* Wm2  = (const float*)d_in[28];
    const float* bm2  = (const float*)d_in[29];
    const float* Wm3  = (const float*)d_in[30];
    const float* bm3  = (const float*)d_in[31];
    float* out = (float*)d_out;
    float* ws = (float*)d_ws;

    const int N = NN, E = EE, Etot = ETOT;

    // workspace layout (floats)
    float* ea_sum   = ws;                                   // 16
    int*   counts   = (int*)(ws + 16);                      // N
    int*   off      = (int*)(ws + 16 + (size_t)N);          // N+16
    int*   cursor   = (int*)(ws + 32 + (size_t)2 * N);      // N
    int*   csr_src  = (int*)(ws + 32 + (size_t)3 * N);      // Etot
    int*   csr_eid  = (int*)(ws + 32 + (size_t)3 * N + Etot); // Etot
    float* A        = ws + 32 + (size_t)3 * N + (size_t)2 * Etot;  // 256N
    float* B        = A + (size_t)256 * N;                  // 256N

    float* xl1 = A;
    float* xr1 = B;
    float* h1  = B;                    // overwrites xr1 in-place (safe: row read before write)
    float* xl2 = A;                    // reuses xl1 (dead after k_fagg1)
    float* xr2 = A + (size_t)64 * N;
    float* h2  = A + (size_t)128 * N;

    hipMemsetAsync(ea_sum, 0, 16 * sizeof(float), stream);
    hipMemsetAsync(counts, 0, (size_t)N * sizeof(int), stream);

    k_ea_reduce<<<256, 256, 0, stream>>>(ea, ea_sum, E);
    k_count<<<(Etot + 255) / 256, 256, 0, stream>>>(ei, counts, E, N);
    k_scan<<<1, 1024, 0, stream>>>(counts, off, cursor, N);
    k_scatter<<<(Etot + 255) / 256, 256, 0, stream>>>(ei, cursor, csr_src, csr_eid, E, N);
    k_ntrans1<<<(N + 31) / 32, 256, 0, stream>>>(x, Wl1, bl1, Wr1, br1, xl1, xr1, N);
    k_fagg1<<<(N + 3) / 4, 256, 0, stream>>>(xl1, xr1, off, csr_src, csr_eid, ea, ea_sum,
                                             We1, att1, bias1, x, Wres,
                                             bn1g, bn1b, bn1m, bn1v, h1, E, N);
    k_xlr2<<<(N + 31) / 32, 256, 0, stream>>>(h1, Wl2, bl2, Wr2, br2, xl2, xr2, N);
    k_fagg2<<<(N + 3) / 4, 256, 0, stream>>>(xl2, xr2, off, csr_src, csr_eid, ea, ea_sum,
                                             We2, att2, bias2,
                                             bn2g, bn2b, bn2m, bn2v, h2, E, N);
    k_mlp<<<(E + 63) / 64, 256, 0, stream>>>(h2, ei, ea, Wm1, bm1, Wm2, bm2, Wm3, bm3, out, E);
}

// Round 5
// 786.872 us; speedup vs baseline: 1.7873x; 1.1042x over previous
//
#include <hip/hip_runtime.h>
#include <hip/hip_bf16.h>
#include <hip/hip_fp16.h>
#include <math.h>

#define NN 50000
#define EE 400000
#define ETOT (NN + EE)

// ---------- helpers ----------
__device__ __forceinline__ float gelu_f(float x) {
    return 0.5f * x * (1.f + erff(x * 0.7071067811865476f));
}
__device__ __forceinline__ float elu_f(float x) {
    return x > 0.f ? x : expm1f(x);
}

// ---------- ea mean (sum) ----------
__global__ __launch_bounds__(256) void k_ea_reduce(const float* __restrict__ ea,
                                                   float* __restrict__ ea_sum, int E) {
    float s[8];
#pragma unroll
    for (int i = 0; i < 8; i++) s[i] = 0.f;
    for (int e = blockIdx.x * blockDim.x + threadIdx.x; e < E; e += gridDim.x * blockDim.x) {
        const float4* p = (const float4*)(ea + (size_t)e * 8);
        float4 a = p[0], b = p[1];
        s[0] += a.x; s[1] += a.y; s[2] += a.z; s[3] += a.w;
        s[4] += b.x; s[5] += b.y; s[6] += b.z; s[7] += b.w;
    }
#pragma unroll
    for (int o = 32; o; o >>= 1)
#pragma unroll
        for (int i = 0; i < 8; i++) s[i] += __shfl_xor(s[i], o, 64);
    __shared__ float sh[4][8];
    int lane = threadIdx.x & 63, w = threadIdx.x >> 6;
    if (lane == 0)
#pragma unroll
        for (int i = 0; i < 8; i++) sh[w][i] = s[i];
    __syncthreads();
    if (threadIdx.x < 8) {
        float v = sh[0][threadIdx.x] + sh[1][threadIdx.x] + sh[2][threadIdx.x] + sh[3][threadIdx.x];
        atomicAdd(ea_sum + threadIdx.x, v);
    }
}

// ---------- CSR build: count / scan / scatter ----------
__global__ __launch_bounds__(256) void k_count(const int* __restrict__ ei, int* __restrict__ counts,
                                               int E, int N) {
    int e = blockIdx.x * blockDim.x + threadIdx.x;
    if (e >= E + N) return;
    int d = (e < E) ? ei[E + e] : (e - E);
    atomicAdd(counts + d, 1);
}

__global__ __launch_bounds__(1024) void k_scan(const int* __restrict__ counts, int* __restrict__ off,
                                               int* __restrict__ cursor, int N) {
    __shared__ int buf[1024];
    int t = threadIdx.x;
    int carry = 0;
    if (t == 0) off[0] = 0;
    for (int base = 0; base < N; base += 1024) {
        int i = base + t;
        int v = (i < N) ? counts[i] : 0;
        buf[t] = v;
        __syncthreads();
        for (int o = 1; o < 1024; o <<= 1) {
            int add = (t >= o) ? buf[t - o] : 0;
            __syncthreads();
            buf[t] += add;
            __syncthreads();
        }
        int incl = buf[t] + carry;
        if (i < N) { off[i + 1] = incl; cursor[i] = incl - v; }
        int tot = buf[1023];
        __syncthreads();
        carry += tot;
    }
}

__global__ __launch_bounds__(256) void k_scatter(const int* __restrict__ ei, int* __restrict__ cursor,
                                                 int* __restrict__ csr_src, int* __restrict__ csr_eid,
                                                 int E, int N) {
    int e = blockIdx.x * blockDim.x + threadIdx.x;
    if (e >= E + N) return;
    int s, d;
    if (e < E) { s = ei[e]; d = ei[E + e]; }
    else { s = d = e - E; }
    int pos = atomicAdd(cursor + d, 1);
    csr_src[pos] = s;
    csr_eid[pos] = e;
}

// ---------- node transform 1: xl1(fp16) = x@Wl1+bl1, xr1(fp32) = x@Wr1+br1 ----------
__global__ __launch_bounds__(256) void k_ntrans1(const float* __restrict__ x,
                                                 const float* __restrict__ Wl, const float* __restrict__ bl,
                                                 const float* __restrict__ Wr, const float* __restrict__ br,
                                                 __half* __restrict__ xl1h, float* __restrict__ xr1, int N) {
    __shared__ float swl[16 * 256];
    __shared__ float swr[16 * 256];
    __shared__ float sx[32 * 16];
    int t = threadIdx.x;
#pragma unroll
    for (int k = 0; k < 16; k++) { swl[k * 256 + t] = Wl[k * 256 + t]; swr[k * 256 + t] = Wr[k * 256 + t]; }
    int n0 = blockIdx.x * 32;
    for (int i = t; i < 32 * 16; i += 256) {
        int n = n0 + (i >> 4);
        sx[i] = (n < N) ? x[(size_t)n * 16 + (i & 15)] : 0.f;
    }
    __syncthreads();
    float bL = bl[t], bR = br[t];
    for (int ni = 0; ni < 32; ni++) {
        int n = n0 + ni;
        if (n >= N) break;
        float al = bL, ar = bR;
#pragma unroll
        for (int k = 0; k < 16; k++) {
            float xv = sx[ni * 16 + k];
            al += xv * swl[k * 256 + t];
            ar += xv * swr[k * 256 + t];
        }
        xl1h[(size_t)n * 256 + t] = __float2half(al);
        xr1[(size_t)n * 256 + t] = ar;
    }
}

// ---------- fused conv1 (online softmax, fp16 gather) ----------
__global__ __launch_bounds__(256) void k_fagg1(const __half* __restrict__ xl1h, const float* __restrict__ xr1,
                                               const int* __restrict__ off, const int* __restrict__ csr_src,
                                               const int* __restrict__ csr_eid,
                                               const float* __restrict__ ea, const float* __restrict__ ea_sum,
                                               const float* __restrict__ We1, const float* __restrict__ att1,
                                               const float* __restrict__ bias1,
                                               const float* __restrict__ x, const float* __restrict__ Wres,
                                               const float* __restrict__ g, const float* __restrict__ bb_,
                                               const float* __restrict__ mm_, const float* __restrict__ vv_,
                                               float* __restrict__ h1,
                                               int E, int N) {
    __shared__ float swe[8 * 256];
    __shared__ float swres[16 * 256];
    int t = threadIdx.x;
    for (int i = t; i < 8 * 256; i += 256) swe[i] = We1[i];
    for (int i = t; i < 16 * 256; i += 256) swres[i] = Wres[i];
    __syncthreads();
    int lane = t & 63, w = t >> 6;
    int node = blockIdx.x * 4 + w;
    if (node >= N) return;
    int c4 = lane * 4;
    int beg = off[node], end = off[node + 1];
    float4 xr4 = *(const float4*)(xr1 + (size_t)node * 256 + c4);
    float4 at4 = *(const float4*)(att1 + c4);
    float invE = 1.f / (float)E;
    float eamean[8];
#pragma unroll
    for (int k = 0; k < 8; k++) eamean[k] = ea_sum[k] * invE;

    float m = -1e30f, sumw = 0.f;
    float4 acc = make_float4(0.f, 0.f, 0.f, 0.f);

    // prefetch first edge (every node has >=1 edge: its self-loop)
    int s = csr_src[beg], e = csr_eid[beg];
    float2 raw = *(const float2*)(xl1h + (size_t)s * 256 + c4);

    for (int i = beg; i < end; i++) {
        int sn = 0, en = 0;
        float2 rawn = make_float2(0.f, 0.f);
        if (i + 1 < end) {
            sn = csr_src[i + 1]; en = csr_eid[i + 1];
            rawn = *(const float2*)(xl1h + (size_t)sn * 256 + c4);
        }
        float eav[8];
        if (e < E) {
#pragma unroll
            for (int k = 0; k < 8; k++) eav[k] = ea[(size_t)e * 8 + k];
        } else {
#pragma unroll
            for (int k = 0; k < 8; k++) eav[k] = eamean[k];
        }
        const __half2* hp = (const __half2*)&raw;
        float2 lo = __half22float2(hp[0]);
        float2 hi = __half22float2(hp[1]);
        float4 xs = make_float4(lo.x, lo.y, hi.x, hi.y);
        float4 ee = make_float4(0.f, 0.f, 0.f, 0.f);
#pragma unroll
        for (int k = 0; k < 8; k++) {
            float a = eav[k];
            float4 wv = *(const float4*)(swe + k * 256 + c4);
            ee.x += a * wv.x; ee.y += a * wv.y; ee.z += a * wv.z; ee.w += a * wv.w;
        }
        float4 v;
        v.x = xs.x + xr4.x + ee.x; v.y = xs.y + xr4.y + ee.y;
        v.z = xs.z + xr4.z + ee.z; v.w = xs.w + xr4.w + ee.w;
        v.x = v.x > 0.f ? v.x : 0.2f * v.x;
        v.y = v.y > 0.f ? v.y : 0.2f * v.y;
        v.z = v.z > 0.f ? v.z : 0.2f * v.z;
        v.w = v.w > 0.f ? v.w : 0.2f * v.w;
        float p = v.x * at4.x + v.y * at4.y + v.z * at4.z + v.w * at4.w;
        p += __shfl_xor(p, 1, 64);
        p += __shfl_xor(p, 2, 64);
        p += __shfl_xor(p, 4, 64);
        p += __shfl_xor(p, 8, 64);
        float mn = fmaxf(m, p);
        float sc = expf(m - mn);
        float wgt = expf(p - mn);
        acc.x = acc.x * sc + wgt * xs.x;
        acc.y = acc.y * sc + wgt * xs.y;
        acc.z = acc.z * sc + wgt * xs.z;
        acc.w = acc.w * sc + wgt * xs.w;
        sumw = sumw * sc + wgt;
        m = mn;
        s = sn; e = en; raw = rawn;
    }
    float inv = 1.f / (sumw + 1e-16f);
    float4 r = make_float4(0.f, 0.f, 0.f, 0.f);
    const float* xp = x + (size_t)node * 16;
#pragma unroll
    for (int k = 0; k < 16; k++) {
        float xv = xp[k];
        float4 wv = *(const float4*)(swres + k * 256 + c4);
        r.x += xv * wv.x; r.y += xv * wv.y; r.z += xv * wv.z; r.w += xv * wv.w;
    }
    float4 bi = *(const float4*)(bias1 + c4);
    float4 g4 = *(const float4*)(g + c4);
    float4 b4 = *(const float4*)(bb_ + c4);
    float4 m4 = *(const float4*)(mm_ + c4);
    float4 v4 = *(const float4*)(vv_ + c4);
    float4 o;
    o.x = acc.x * inv + bi.x; o.y = acc.y * inv + bi.y;
    o.z = acc.z * inv + bi.z; o.w = acc.w * inv + bi.w;
    o.x = (o.x - m4.x) * rsqrtf(v4.x + 1e-5f) * g4.x + b4.x + r.x;
    o.y = (o.y - m4.y) * rsqrtf(v4.y + 1e-5f) * g4.y + b4.y + r.y;
    o.z = (o.z - m4.z) * rsqrtf(v4.z + 1e-5f) * g4.z + b4.z + r.z;
    o.w = (o.w - m4.w) * rsqrtf(v4.w + 1e-5f) * g4.w + b4.w + r.w;
    o.x = elu_f(o.x); o.y = elu_f(o.y); o.z = elu_f(o.z); o.w = elu_f(o.w);
    *(float4*)(h1 + (size_t)node * 256 + c4) = o;
}

// ---------- xl2(fp16) = h1@Wl2+bl2, xr2(fp32) = h1@Wr2+br2 ----------
__global__ __launch_bounds__(256) void k_xlr2(const float* __restrict__ h1,
                                              const float* __restrict__ Wl2, const float* __restrict__ bl2,
                                              const float* __restrict__ Wr2, const float* __restrict__ br2,
                                              __half* __restrict__ xl2h, float* __restrict__ xr2, int N) {
    __shared__ float sh[32][32];    // [kk][node]
    __shared__ float sw[32][128];   // [kk][col]
    int t = threadIdx.x;
    int tr = t >> 5, tc = t & 31;
    int n0 = blockIdx.x * 32;
    float acc[4][4];
#pragma unroll
    for (int i = 0; i < 4; i++)
#pragma unroll
        for (int j = 0; j < 4; j++) acc[i][j] = 0.f;
    for (int k0 = 0; k0 < 256; k0 += 32) {
        {
            int n = t >> 3, kk0 = (t & 7) * 4;
            int gn = n0 + n;
            float4 hv = make_float4(0.f, 0.f, 0.f, 0.f);
            if (gn < N) hv = *(const float4*)(h1 + (size_t)gn * 256 + k0 + kk0);
            sh[kk0 + 0][n] = hv.x; sh[kk0 + 1][n] = hv.y; sh[kk0 + 2][n] = hv.z; sh[kk0 + 3][n] = hv.w;
        }
        for (int i = t; i < 32 * 128; i += 256) {
            int kk = i >> 7, c = i & 127;
            sw[kk][c] = (c < 64) ? Wl2[(size_t)(k0 + kk) * 64 + c] : Wr2[(size_t)(k0 + kk) * 64 + (c - 64)];
        }
        __syncthreads();
#pragma unroll
        for (int kk = 0; kk < 32; kk++) {
            float4 hv = *(const float4*)&sh[kk][tr * 4];
            float4 wv = *(const float4*)&sw[kk][tc * 4];
            float hh[4] = { hv.x, hv.y, hv.z, hv.w };
            float wwv[4] = { wv.x, wv.y, wv.z, wv.w };
#pragma unroll
            for (int i = 0; i < 4; i++)
#pragma unroll
                for (int j = 0; j < 4; j++) acc[i][j] += hh[i] * wwv[j];
        }
        __syncthreads();
    }
#pragma unroll
    for (int i = 0; i < 4; i++) {
        int gn = n0 + tr * 4 + i;
        if (gn >= N) continue;
#pragma unroll
        for (int j = 0; j < 4; j++) {
            int c = tc * 4 + j;
            float vv = acc[i][j];
            if (c < 64) xl2h[(size_t)gn * 64 + c] = __float2half(vv + bl2[c]);
            else        xr2[(size_t)gn * 64 + (c - 64)] = vv + br2[c - 64];
        }
    }
}

// ---------- fused conv2 (online softmax, fp16 gather) ----------
__global__ __launch_bounds__(256) void k_fagg2(const __half* __restrict__ xl2h, const float* __restrict__ xr2,
                                               const int* __restrict__ off, const int* __restrict__ csr_src,
                                               const int* __restrict__ csr_eid,
                                               const float* __restrict__ ea, const float* __restrict__ ea_sum,
                                               const float* __restrict__ We2, const float* __restrict__ att2,
                                               const float* __restrict__ bias2,
                                               const float* __restrict__ g, const float* __restrict__ bb_,
                                               const float* __restrict__ mm_, const float* __restrict__ vv_,
                                               __half* __restrict__ h2h,
                                               int E, int N) {
    __shared__ float swe[8 * 64];
    int t = threadIdx.x;
    if (t < 512) swe[t] = We2[t];
    __syncthreads();
    int lane = t & 63, w = t >> 6;
    int node = blockIdx.x * 4 + w;
    if (node >= N) return;
    int beg = off[node], end = off[node + 1];
    float xr = xr2[(size_t)node * 64 + lane];
    float at = att2[lane];
    float invE = 1.f / (float)E;
    float eamean[8];
#pragma unroll
    for (int k = 0; k < 8; k++) eamean[k] = ea_sum[k] * invE;

    float m = -1e30f, sumw = 0.f, acc = 0.f;
    int s = csr_src[beg], e = csr_eid[beg];
    float xs = __half2float(xl2h[(size_t)s * 64 + lane]);

    for (int i = beg; i < end; i++) {
        int sn = 0, en = 0;
        float xsn = 0.f;
        if (i + 1 < end) {
            sn = csr_src[i + 1]; en = csr_eid[i + 1];
            xsn = __half2float(xl2h[(size_t)sn * 64 + lane]);
        }
        float eav[8];
        if (e < E) {
#pragma unroll
            for (int k = 0; k < 8; k++) eav[k] = ea[(size_t)e * 8 + k];
        } else {
#pragma unroll
            for (int k = 0; k < 8; k++) eav[k] = eamean[k];
        }
        float v = xs + xr;
#pragma unroll
        for (int k = 0; k < 8; k++) v += eav[k] * swe[k * 64 + lane];
        v = v > 0.f ? v : 0.2f * v;
        float p = v * at;
#pragma unroll
        for (int o = 32; o; o >>= 1) p += __shfl_xor(p, o, 64);
        float mn = fmaxf(m, p);
        float sc = expf(m - mn);
        float wgt = expf(p - mn);
        acc = acc * sc + wgt * xs;
        sumw = sumw * sc + wgt;
        m = mn;
        s = sn; e = en; xs = xsn;
    }
    float val = acc / (sumw + 1e-16f) + bias2[lane];
    val = (val - mm_[lane]) * rsqrtf(vv_[lane] + 1e-5f) * g[lane] + bb_[lane];
    h2h[(size_t)node * 64 + lane] = __float2half(elu_f(val));
}

// ---------- edge MLP head: tiled GEMM, 64 edges per block, fp16 h2 gather ----------
__global__ __launch_bounds__(256) void k_mlp(const __half* __restrict__ h2h, const int* __restrict__ ei,
                                             const float* __restrict__ ea,
                                             const float* __restrict__ Wm1, const float* __restrict__ bm1,
                                             const float* __restrict__ Wm2, const float* __restrict__ bm2,
                                             const float* __restrict__ Wm3, const float* __restrict__ bm3,
                                             float* __restrict__ out, int E) {
    __shared__ float sw1[136 * 64];
    __shared__ float sw2[64 * 32];
    __shared__ float sw3[32];
    __shared__ int sre[64], sce[64];
    __shared__ float sa[64 * 140];
    int t = threadIdx.x;
    for (int i = t; i < 136 * 64; i += 256) sw1[i] = Wm1[i];
    for (int i = t; i < 64 * 32; i += 256) sw2[i] = Wm2[i];
    if (t < 32) sw3[t] = Wm3[t];
    int e0 = blockIdx.x * 64;
    if (t < 64) {
        int e = e0 + t;
        if (e < E) { sre[t] = ei[e]; sce[t] = ei[E + e]; }
        else { sre[t] = 0; sce[t] = 0; }
    }
    __syncthreads();
    // stage er tile: per edge 18 chunks: 8x(8 halfs from h2h[r]) + 8x(8 halfs from h2h[c]) + 2x(float4 ea)
    for (int i = t; i < 64 * 18; i += 256) {
        int el = i / 18, q = i - el * 18;
        float* dst = sa + el * 140;
        if (q < 16) {
            int n = (q < 8) ? sre[el] : sce[el];
            int qq = q & 7;
            float4 hv = *(const float4*)(h2h + (size_t)n * 64 + qq * 8);
            const __half2* hp = (const __half2*)&hv;
            float2 f0 = __half22float2(hp[0]);
            float2 f1 = __half22float2(hp[1]);
            float2 f2 = __half22float2(hp[2]);
            float2 f3 = __half22float2(hp[3]);
            int base = (q < 8) ? qq * 8 : 64 + qq * 8;
            dst[base + 0] = f0.x; dst[base + 1] = f0.y;
            dst[base + 2] = f1.x; dst[base + 3] = f1.y;
            dst[base + 4] = f2.x; dst[base + 5] = f2.y;
            dst[base + 6] = f3.x; dst[base + 7] = f3.y;
        } else {
            int qq = q - 16;
            float4 v = *(const float4*)(ea + (size_t)(e0 + el) * 8 + qq * 4);
            *(float4*)(dst + 128 + qq * 4) = v;
        }
    }
    __syncthreads();
    int tr = t >> 4, tc = t & 15;
    float acc[4][4];
#pragma unroll
    for (int j = 0; j < 4; j++) {
        float bv = bm1[tc * 4 + j];
#pragma unroll
        for (int i = 0; i < 4; i++) acc[i][j] = bv;
    }
    for (int k = 0; k < 136; k++) {
        float4 bv = *(const float4*)(sw1 + k * 64 + tc * 4);
        float a0 = sa[(tr * 4 + 0) * 140 + k];
        float a1 = sa[(tr * 4 + 1) * 140 + k];
        float a2 = sa[(tr * 4 + 2) * 140 + k];
        float a3 = sa[(tr * 4 + 3) * 140 + k];
        acc[0][0] += a0 * bv.x; acc[0][1] += a0 * bv.y; acc[0][2] += a0 * bv.z; acc[0][3] += a0 * bv.w;
        acc[1][0] += a1 * bv.x; acc[1][1] += a1 * bv.y; acc[1][2] += a1 * bv.z; acc[1][3] += a1 * bv.w;
        acc[2][0] += a2 * bv.x; acc[2][1] += a2 * bv.y; acc[2][2] += a2 * bv.z; acc[2][3] += a2 * bv.w;
        acc[3][0] += a3 * bv.x; acc[3][1] += a3 * bv.y; acc[3][2] += a3 * bv.z; acc[3][3] += a3 * bv.w;
    }
    __syncthreads();
#pragma unroll
    for (int i = 0; i < 4; i++) {
        float4 z;
        z.x = gelu_f(acc[i][0]); z.y = gelu_f(acc[i][1]);
        z.z = gelu_f(acc[i][2]); z.w = gelu_f(acc[i][3]);
        *(float4*)(sa + (tr * 4 + i) * 140 + tc * 4) = z;
    }
    __syncthreads();
    float acc2[4][2];
#pragma unroll
    for (int j = 0; j < 2; j++) {
        float bv = bm2[tc * 2 + j];
#pragma unroll
        for (int i = 0; i < 4; i++) acc2[i][j] = bv;
    }
    for (int k = 0; k < 64; k++) {
        float2 bv = *(const float2*)(sw2 + k * 32 + tc * 2);
        float a0 = sa[(tr * 4 + 0) * 140 + k];
        float a1 = sa[(tr * 4 + 1) * 140 + k];
        float a2 = sa[(tr * 4 + 2) * 140 + k];
        float a3 = sa[(tr * 4 + 3) * 140 + k];
        acc2[0][0] += a0 * bv.x; acc2[0][1] += a0 * bv.y;
        acc2[1][0] += a1 * bv.x; acc2[1][1] += a1 * bv.y;
        acc2[2][0] += a2 * bv.x; acc2[2][1] += a2 * bv.y;
        acc2[3][0] += a3 * bv.x; acc2[3][1] += a3 * bv.y;
    }
    __syncthreads();
#pragma unroll
    for (int i = 0; i < 4; i++)
#pragma unroll
        for (int j = 0; j < 2; j++)
            sa[(tr * 4 + i) * 140 + 96 + tc * 2 + j] = gelu_f(acc2[i][j]);
    __syncthreads();
    if (t < 64) {
        float s = bm3[0];
#pragma unroll
        for (int k = 0; k < 32; k++) s += sa[t * 140 + 96 + k] * sw3[k];
        int e = e0 + t;
        if (e < E) out[e] = 1.f / (1.f + expf(-s));
    }
}

extern "C" void kernel_launch(void* const* d_in, const int* in_sizes, int n_in,
                              void* d_out, int out_size, void* d_ws, size_t ws_size,
                              hipStream_t stream) {
    const float* x    = (const float*)d_in[0];
    const int*   ei   = (const int*)d_in[1];
    const float* ea   = (const float*)d_in[2];
    const float* Wl1  = (const float*)d_in[3];
    const float* bl1  = (const float*)d_in[4];
    const float* Wr1  = (const float*)d_in[5];
    const float* br1  = (const float*)d_in[6];
    const float* We1  = (const float*)d_in[7];
    const float* att1 = (const float*)d_in[8];
    const float* bias1= (const float*)d_in[9];
    const float* Wl2  = (const float*)d_in[10];
    const float* bl2  = (const float*)d_in[11];
    const float* Wr2  = (const float*)d_in[12];
    const float* br2  = (const float*)d_in[13];
    const float* We2  = (const float*)d_in[14];
    const float* att2 = (const float*)d_in[15];
    const float* bias2= (const float*)d_in[16];
    const float* bn1g = (const float*)d_in[17];
    const float* bn1b = (const float*)d_in[18];
    const float* bn1m = (const float*)d_in[19];
    const float* bn1v = (const float*)d_in[20];
    const float* bn2g = (const float*)d_in[21];
    const float* bn2b = (const float*)d_in[22];
    const float* bn2m = (const float*)d_in[23];
    const float* bn2v = (const float*)d_in[24];
    const float* Wres = (const float*)d_in[25];
    const float* Wm1  = (const float*)d_in[26];
    const float* bm1  = (const float*)d_in[27];
    const float* Wm2  = (const float*)d_in[28];
    const float* bm2  = (const float*)d_in[29];
    const float* Wm3  = (const float*)d_in[30];
    const float* bm3  = (const float*)d_in[31];
    float* out = (float*)d_out;
    float* ws = (float*)d_ws;

    const int N = NN, E = EE, Etot = ETOT;

    // workspace layout (floats)
    float* ea_sum   = ws;                                     // 16
    int*   counts   = (int*)(ws + 16);                        // N
    int*   off      = (int*)(ws + 16 + (size_t)N);            // N+16
    int*   cursor   = (int*)(ws + 32 + (size_t)2 * N);        // N
    int*   csr_src  = (int*)(ws + 32 + (size_t)3 * N);        // Etot
    int*   csr_eid  = (int*)(ws + 32 + (size_t)3 * N + Etot); // Etot
    size_t base     = 32 + (size_t)3 * N + (size_t)2 * Etot;
    __half* xl1h    = (__half*)(ws + base);                   // 256N halfs = 128N floats
    __half* xl2h    = xl1h;                                   // reuses (xl1h dead after k_fagg1)
    __half* h2h     = (__half*)(ws + base + (size_t)128 * N); // 64N halfs = 32N floats
    float* xr1      = ws + base + (size_t)160 * N;            // 256N floats
    float* h1       = xr1;                                    // in-place (row read before write)
    float* xr2      = xr1 + (size_t)256 * N;                  // 64N floats

    hipMemsetAsync(ea_sum, 0, 16 * sizeof(float), stream);
    hipMemsetAsync(counts, 0, (size_t)N * sizeof(int), stream);

    k_ea_reduce<<<256, 256, 0, stream>>>(ea, ea_sum, E);
    k_count<<<(Etot + 255) / 256, 256, 0, stream>>>(ei, counts, E, N);
    k_scan<<<1, 1024, 0, stream>>>(counts, off, cursor, N);
    k_scatter<<<(Etot + 255) / 256, 256, 0, stream>>>(ei, cursor, csr_src, csr_eid, E, N);
    k_ntrans1<<<(N + 31) / 32, 256, 0, stream>>>(x, Wl1, bl1, Wr1, br1, xl1h, xr1, N);
    k_fagg1<<<(N + 3) / 4, 256, 0, stream>>>(xl1h, xr1, off, csr_src, csr_eid, ea, ea_sum,
                                             We1, att1, bias1, x, Wres,
                                             bn1g, bn1b, bn1m, bn1v, h1, E, N);
    k_xlr2<<<(N + 31) / 32, 256, 0, stream>>>(h1, Wl2, bl2, Wr2, br2, xl2h, xr2, N);
    k_fagg2<<<(N + 3) / 4, 256, 0, stream>>>(xl2h, xr2, off, csr_src, csr_eid, ea, ea_sum,
                                             We2, att2, bias2,
                                             bn2g, bn2b, bn2m, bn2v, h2h, E, N);
    k_mlp<<<(E + 63) / 64, 256, 0, stream>>>(h2h, ei, ea, Wm1, bm1, Wm2, bm2, Wm3, bm3, out, E);
}

// Round 6
// 647.651 us; speedup vs baseline: 2.1715x; 1.2150x over previous
//
#include <hip/hip_runtime.h>
#include <hip/hip_bf16.h>
#include <hip/hip_fp16.h>
#include <math.h>

#define NN 50000
#define EE 400000
#define ETOT (NN + EE)

// ---------- helpers ----------
__device__ __forceinline__ float gelu_f(float x) {
    return 0.5f * x * (1.f + erff(x * 0.7071067811865476f));
}
__device__ __forceinline__ float elu_f(float x) {
    return x > 0.f ? x : expm1f(x);
}

// ---------- ea mean (sum) ----------
__global__ __launch_bounds__(256) void k_ea_reduce(const float* __restrict__ ea,
                                                   float* __restrict__ ea_sum, int E) {
    float s[8];
#pragma unroll
    for (int i = 0; i < 8; i++) s[i] = 0.f;
    for (int e = blockIdx.x * blockDim.x + threadIdx.x; e < E; e += gridDim.x * blockDim.x) {
        const float4* p = (const float4*)(ea + (size_t)e * 8);
        float4 a = p[0], b = p[1];
        s[0] += a.x; s[1] += a.y; s[2] += a.z; s[3] += a.w;
        s[4] += b.x; s[5] += b.y; s[6] += b.z; s[7] += b.w;
    }
#pragma unroll
    for (int o = 32; o; o >>= 1)
#pragma unroll
        for (int i = 0; i < 8; i++) s[i] += __shfl_xor(s[i], o, 64);
    __shared__ float sh[4][8];
    int lane = threadIdx.x & 63, w = threadIdx.x >> 6;
    if (lane == 0)
#pragma unroll
        for (int i = 0; i < 8; i++) sh[w][i] = s[i];
    __syncthreads();
    if (threadIdx.x < 8) {
        float v = sh[0][threadIdx.x] + sh[1][threadIdx.x] + sh[2][threadIdx.x] + sh[3][threadIdx.x];
        atomicAdd(ea_sum + threadIdx.x, v);
    }
}

// ---------- CSR build: count / scan / scatter ----------
__global__ __launch_bounds__(256) void k_count(const int* __restrict__ ei, int* __restrict__ counts,
                                               int E, int N) {
    int e = blockIdx.x * blockDim.x + threadIdx.x;
    if (e >= E + N) return;
    int d = (e < E) ? ei[E + e] : (e - E);
    atomicAdd(counts + d, 1);
}

__global__ __launch_bounds__(1024) void k_scan(const int* __restrict__ counts, int* __restrict__ off,
                                               int* __restrict__ cursor, int N) {
    __shared__ int buf[1024];
    int t = threadIdx.x;
    int carry = 0;
    if (t == 0) off[0] = 0;
    for (int base = 0; base < N; base += 1024) {
        int i = base + t;
        int v = (i < N) ? counts[i] : 0;
        buf[t] = v;
        __syncthreads();
        for (int o = 1; o < 1024; o <<= 1) {
            int add = (t >= o) ? buf[t - o] : 0;
            __syncthreads();
            buf[t] += add;
            __syncthreads();
        }
        int incl = buf[t] + carry;
        if (i < N) { off[i + 1] = incl; cursor[i] = incl - v; }
        int tot = buf[1023];
        __syncthreads();
        carry += tot;
    }
}

__global__ __launch_bounds__(256) void k_scatter(const int* __restrict__ ei, int* __restrict__ cursor,
                                                 int* __restrict__ csr_src, int* __restrict__ csr_eid,
                                                 int E, int N) {
    int e = blockIdx.x * blockDim.x + threadIdx.x;
    if (e >= E + N) return;
    int s, d;
    if (e < E) { s = ei[e]; d = ei[E + e]; }
    else { s = d = e - E; }
    int pos = atomicAdd(cursor + d, 1);
    csr_src[pos] = s;
    csr_eid[pos] = e;
}

// ---------- node transform 1: xl1(fp16) = x@Wl1+bl1, xr1(fp32) = x@Wr1+br1 ----------
__global__ __launch_bounds__(256) void k_ntrans1(const float* __restrict__ x,
                                                 const float* __restrict__ Wl, const float* __restrict__ bl,
                                                 const float* __restrict__ Wr, const float* __restrict__ br,
                                                 __half* __restrict__ xl1h, float* __restrict__ xr1, int N) {
    __shared__ float swl[16 * 256];
    __shared__ float swr[16 * 256];
    __shared__ float sx[32 * 16];
    int t = threadIdx.x;
#pragma unroll
    for (int k = 0; k < 16; k++) { swl[k * 256 + t] = Wl[k * 256 + t]; swr[k * 256 + t] = Wr[k * 256 + t]; }
    int n0 = blockIdx.x * 32;
    for (int i = t; i < 32 * 16; i += 256) {
        int n = n0 + (i >> 4);
        sx[i] = (n < N) ? x[(size_t)n * 16 + (i & 15)] : 0.f;
    }
    __syncthreads();
    float bL = bl[t], bR = br[t];
    for (int ni = 0; ni < 32; ni++) {
        int n = n0 + ni;
        if (n >= N) break;
        float al = bL, ar = bR;
#pragma unroll
        for (int k = 0; k < 16; k++) {
            float xv = sx[ni * 16 + k];
            al += xv * swl[k * 256 + t];
            ar += xv * swr[k * 256 + t];
        }
        xl1h[(size_t)n * 256 + t] = __float2half(al);
        xr1[(size_t)n * 256 + t] = ar;
    }
}

// ---------- fused conv1: zero-LDS, chunked index/ea broadcast, depth-3 row prefetch ----------
__global__ __launch_bounds__(256) void k_fagg1(const __half* __restrict__ xl1h, const float* __restrict__ xr1,
                                               const int* __restrict__ off, const int* __restrict__ csr_src,
                                               const int* __restrict__ csr_eid,
                                               const float* __restrict__ ea, const float* __restrict__ ea_sum,
                                               const float* __restrict__ We1, const float* __restrict__ att1,
                                               const float* __restrict__ bias1,
                                               const float* __restrict__ x, const float* __restrict__ Wres,
                                               const float* __restrict__ g, const float* __restrict__ bb_,
                                               const float* __restrict__ mm_, const float* __restrict__ vv_,
                                               float* __restrict__ h1,
                                               int E, int N) {
    int t = threadIdx.x;
    int lane = t & 63, w = t >> 6;
    int node = blockIdx.x * 4 + w;
    if (node >= N) return;
    int c4 = lane * 4;
    // lane-private We1 slice: [8][4] in registers
    float4 we[8];
#pragma unroll
    for (int k = 0; k < 8; k++) we[k] = *(const float4*)(We1 + k * 256 + c4);
    float4 xr4 = *(const float4*)(xr1 + (size_t)node * 256 + c4);
    float4 at4 = *(const float4*)(att1 + c4);
    float invE = 1.f / (float)E;
    float4 eam0, eam1;
    eam0.x = ea_sum[0] * invE; eam0.y = ea_sum[1] * invE;
    eam0.z = ea_sum[2] * invE; eam0.w = ea_sum[3] * invE;
    eam1.x = ea_sum[4] * invE; eam1.y = ea_sum[5] * invE;
    eam1.z = ea_sum[6] * invE; eam1.w = ea_sum[7] * invE;

    int beg = off[node], end = off[node + 1];
    float m = -1e30f, sumw = 0.f;
    float4 acc = make_float4(0.f, 0.f, 0.f, 0.f);

    int cb = beg;
    while (cb < end) {
        int cnt = end - cb; if (cnt > 64) cnt = 64;
        // chunk load: lane j owns edge cb+j
        int sl = 0;
        float4 ba = eam0, bb4 = eam1;
        if (lane < cnt) {
            sl = csr_src[cb + lane];
            int el = csr_eid[cb + lane];
            if (el < E) {
                ba  = *(const float4*)(ea + (size_t)el * 8);
                bb4 = *(const float4*)(ea + (size_t)el * 8 + 4);
            }
        }
        // depth-3 rotating row prefetch
        float2 r0 = make_float2(0.f, 0.f), r1 = r0, r2 = r0;
        {
            int s0 = __shfl(sl, 0, 64);
            r0 = *(const float2*)(xl1h + (size_t)s0 * 256 + c4);
            if (cnt > 1) { int s1 = __shfl(sl, 1, 64); r1 = *(const float2*)(xl1h + (size_t)s1 * 256 + c4); }
            if (cnt > 2) { int s2 = __shfl(sl, 2, 64); r2 = *(const float2*)(xl1h + (size_t)s2 * 256 + c4); }
        }
        for (int j = 0; j < cnt; j++) {
            float2 cur = r0;
            r0 = r1; r1 = r2;
            if (j + 3 < cnt) {
                int s3 = __shfl(sl, j + 3, 64);
                r2 = *(const float2*)(xl1h + (size_t)s3 * 256 + c4);
            }
            float eav[8];
            eav[0] = __shfl(ba.x, j, 64);  eav[1] = __shfl(ba.y, j, 64);
            eav[2] = __shfl(ba.z, j, 64);  eav[3] = __shfl(ba.w, j, 64);
            eav[4] = __shfl(bb4.x, j, 64); eav[5] = __shfl(bb4.y, j, 64);
            eav[6] = __shfl(bb4.z, j, 64); eav[7] = __shfl(bb4.w, j, 64);
            const __half2* hp = (const __half2*)&cur;
            float2 lo = __half22float2(hp[0]);
            float2 hi = __half22float2(hp[1]);
            float4 xs = make_float4(lo.x, lo.y, hi.x, hi.y);
            float4 ee = make_float4(0.f, 0.f, 0.f, 0.f);
#pragma unroll
            for (int k = 0; k < 8; k++) {
                ee.x += eav[k] * we[k].x; ee.y += eav[k] * we[k].y;
                ee.z += eav[k] * we[k].z; ee.w += eav[k] * we[k].w;
            }
            float4 v;
            v.x = xs.x + xr4.x + ee.x; v.y = xs.y + xr4.y + ee.y;
            v.z = xs.z + xr4.z + ee.z; v.w = xs.w + xr4.w + ee.w;
            v.x = v.x > 0.f ? v.x : 0.2f * v.x;
            v.y = v.y > 0.f ? v.y : 0.2f * v.y;
            v.z = v.z > 0.f ? v.z : 0.2f * v.z;
            v.w = v.w > 0.f ? v.w : 0.2f * v.w;
            float p = v.x * at4.x + v.y * at4.y + v.z * at4.z + v.w * at4.w;
            p += __shfl_xor(p, 1, 64);
            p += __shfl_xor(p, 2, 64);
            p += __shfl_xor(p, 4, 64);
            p += __shfl_xor(p, 8, 64);
            float mn = fmaxf(m, p);
            float sc = expf(m - mn);
            float wgt = expf(p - mn);
            acc.x = acc.x * sc + wgt * xs.x;
            acc.y = acc.y * sc + wgt * xs.y;
            acc.z = acc.z * sc + wgt * xs.z;
            acc.w = acc.w * sc + wgt * xs.w;
            sumw = sumw * sc + wgt;
            m = mn;
        }
        cb += cnt;
    }
    float inv = 1.f / (sumw + 1e-16f);
    // residual x@Wres (Wres read from global; L2-resident)
    float4 r = make_float4(0.f, 0.f, 0.f, 0.f);
#pragma unroll
    for (int q = 0; q < 4; q++) {
        float4 xq = *(const float4*)(x + (size_t)node * 16 + q * 4);
        float xa[4] = { xq.x, xq.y, xq.z, xq.w };
#pragma unroll
        for (int kk = 0; kk < 4; kk++) {
            float4 wv = *(const float4*)(Wres + (size_t)(q * 4 + kk) * 256 + c4);
            r.x += xa[kk] * wv.x; r.y += xa[kk] * wv.y;
            r.z += xa[kk] * wv.z; r.w += xa[kk] * wv.w;
        }
    }
    float4 bi = *(const float4*)(bias1 + c4);
    float4 g4 = *(const float4*)(g + c4);
    float4 b4 = *(const float4*)(bb_ + c4);
    float4 m4 = *(const float4*)(mm_ + c4);
    float4 v4 = *(const float4*)(vv_ + c4);
    float4 o;
    o.x = acc.x * inv + bi.x; o.y = acc.y * inv + bi.y;
    o.z = acc.z * inv + bi.z; o.w = acc.w * inv + bi.w;
    o.x = (o.x - m4.x) * rsqrtf(v4.x + 1e-5f) * g4.x + b4.x + r.x;
    o.y = (o.y - m4.y) * rsqrtf(v4.y + 1e-5f) * g4.y + b4.y + r.y;
    o.z = (o.z - m4.z) * rsqrtf(v4.z + 1e-5f) * g4.z + b4.z + r.z;
    o.w = (o.w - m4.w) * rsqrtf(v4.w + 1e-5f) * g4.w + b4.w + r.w;
    o.x = elu_f(o.x); o.y = elu_f(o.y); o.z = elu_f(o.z); o.w = elu_f(o.w);
    *(float4*)(h1 + (size_t)node * 256 + c4) = o;
}

// ---------- xl2(fp16) = h1@Wl2+bl2, xr2(fp32) = h1@Wr2+br2 ----------
__global__ __launch_bounds__(256) void k_xlr2(const float* __restrict__ h1,
                                              const float* __restrict__ Wl2, const float* __restrict__ bl2,
                                              const float* __restrict__ Wr2, const float* __restrict__ br2,
                                              __half* __restrict__ xl2h, float* __restrict__ xr2, int N) {
    __shared__ float sh[32][32];    // [kk][node]
    __shared__ float sw[32][128];   // [kk][col]
    int t = threadIdx.x;
    int tr = t >> 5, tc = t & 31;
    int n0 = blockIdx.x * 32;
    float acc[4][4];
#pragma unroll
    for (int i = 0; i < 4; i++)
#pragma unroll
        for (int j = 0; j < 4; j++) acc[i][j] = 0.f;
    for (int k0 = 0; k0 < 256; k0 += 32) {
        {
            int n = t >> 3, kk0 = (t & 7) * 4;
            int gn = n0 + n;
            float4 hv = make_float4(0.f, 0.f, 0.f, 0.f);
            if (gn < N) hv = *(const float4*)(h1 + (size_t)gn * 256 + k0 + kk0);
            sh[kk0 + 0][n] = hv.x; sh[kk0 + 1][n] = hv.y; sh[kk0 + 2][n] = hv.z; sh[kk0 + 3][n] = hv.w;
        }
        for (int i = t; i < 32 * 128; i += 256) {
            int kk = i >> 7, c = i & 127;
            sw[kk][c] = (c < 64) ? Wl2[(size_t)(k0 + kk) * 64 + c] : Wr2[(size_t)(k0 + kk) * 64 + (c - 64)];
        }
        __syncthreads();
#pragma unroll
        for (int kk = 0; kk < 32; kk++) {
            float4 hv = *(const float4*)&sh[kk][tr * 4];
            float4 wv = *(const float4*)&sw[kk][tc * 4];
            float hh[4] = { hv.x, hv.y, hv.z, hv.w };
            float wwv[4] = { wv.x, wv.y, wv.z, wv.w };
#pragma unroll
            for (int i = 0; i < 4; i++)
#pragma unroll
                for (int j = 0; j < 4; j++) acc[i][j] += hh[i] * wwv[j];
        }
        __syncthreads();
    }
#pragma unroll
    for (int i = 0; i < 4; i++) {
        int gn = n0 + tr * 4 + i;
        if (gn >= N) continue;
#pragma unroll
        for (int j = 0; j < 4; j++) {
            int c = tc * 4 + j;
            float vv = acc[i][j];
            if (c < 64) xl2h[(size_t)gn * 64 + c] = __float2half(vv + bl2[c]);
            else        xr2[(size_t)gn * 64 + (c - 64)] = vv + br2[c - 64];
        }
    }
}

// ---------- fused conv2: zero-LDS, chunked broadcast, depth-3 prefetch ----------
__global__ __launch_bounds__(256) void k_fagg2(const __half* __restrict__ xl2h, const float* __restrict__ xr2,
                                               const int* __restrict__ off, const int* __restrict__ csr_src,
                                               const int* __restrict__ csr_eid,
                                               const float* __restrict__ ea, const float* __restrict__ ea_sum,
                                               const float* __restrict__ We2, const float* __restrict__ att2,
                                               const float* __restrict__ bias2,
                                               const float* __restrict__ g, const float* __restrict__ bb_,
                                               const float* __restrict__ mm_, const float* __restrict__ vv_,
                                               __half* __restrict__ h2h,
                                               int E, int N) {
    int t = threadIdx.x;
    int lane = t & 63, w = t >> 6;
    int node = blockIdx.x * 4 + w;
    if (node >= N) return;
    float we[8];
#pragma unroll
    for (int k = 0; k < 8; k++) we[k] = We2[k * 64 + lane];
    float xr = xr2[(size_t)node * 64 + lane];
    float at = att2[lane];
    float invE = 1.f / (float)E;
    float4 eam0, eam1;
    eam0.x = ea_sum[0] * invE; eam0.y = ea_sum[1] * invE;
    eam0.z = ea_sum[2] * invE; eam0.w = ea_sum[3] * invE;
    eam1.x = ea_sum[4] * invE; eam1.y = ea_sum[5] * invE;
    eam1.z = ea_sum[6] * invE; eam1.w = ea_sum[7] * invE;

    int beg = off[node], end = off[node + 1];
    float m = -1e30f, sumw = 0.f, acc = 0.f;

    int cb = beg;
    while (cb < end) {
        int cnt = end - cb; if (cnt > 64) cnt = 64;
        int sl = 0;
        float4 ba = eam0, bb4 = eam1;
        if (lane < cnt) {
            sl = csr_src[cb + lane];
            int el = csr_eid[cb + lane];
            if (el < E) {
                ba  = *(const float4*)(ea + (size_t)el * 8);
                bb4 = *(const float4*)(ea + (size_t)el * 8 + 4);
            }
        }
        float r0 = 0.f, r1 = 0.f, r2 = 0.f;
        {
            int s0 = __shfl(sl, 0, 64);
            r0 = __half2float(xl2h[(size_t)s0 * 64 + lane]);
            if (cnt > 1) { int s1 = __shfl(sl, 1, 64); r1 = __half2float(xl2h[(size_t)s1 * 64 + lane]); }
            if (cnt > 2) { int s2 = __shfl(sl, 2, 64); r2 = __half2float(xl2h[(size_t)s2 * 64 + lane]); }
        }
        for (int j = 0; j < cnt; j++) {
            float xs = r0;
            r0 = r1; r1 = r2;
            if (j + 3 < cnt) {
                int s3 = __shfl(sl, j + 3, 64);
                r2 = __half2float(xl2h[(size_t)s3 * 64 + lane]);
            }
            float eav[8];
            eav[0] = __shfl(ba.x, j, 64);  eav[1] = __shfl(ba.y, j, 64);
            eav[2] = __shfl(ba.z, j, 64);  eav[3] = __shfl(ba.w, j, 64);
            eav[4] = __shfl(bb4.x, j, 64); eav[5] = __shfl(bb4.y, j, 64);
            eav[6] = __shfl(bb4.z, j, 64); eav[7] = __shfl(bb4.w, j, 64);
            float v = xs + xr;
#pragma unroll
            for (int k = 0; k < 8; k++) v += eav[k] * we[k];
            v = v > 0.f ? v : 0.2f * v;
            float p = v * at;
#pragma unroll
            for (int o = 32; o; o >>= 1) p += __shfl_xor(p, o, 64);
            float mn = fmaxf(m, p);
            float sc = expf(m - mn);
            float wgt = expf(p - mn);
            acc = acc * sc + wgt * xs;
            sumw = sumw * sc + wgt;
            m = mn;
        }
        cb += cnt;
    }
    float val = acc / (sumw + 1e-16f) + bias2[lane];
    val = (val - mm_[lane]) * rsqrtf(vv_[lane] + 1e-5f) * g[lane] + bb_[lane];
    h2h[(size_t)node * 64 + lane] = __float2half(elu_f(val));
}

// ---------- edge MLP head: tiled GEMM, 64 edges per block, fp16 h2 gather ----------
__global__ __launch_bounds__(256) void k_mlp(const __half* __restrict__ h2h, const int* __restrict__ ei,
                                             const float* __restrict__ ea,
                                             const float* __restrict__ Wm1, const float* __restrict__ bm1,
                                             const float* __restrict__ Wm2, const float* __restrict__ bm2,
                                             const float* __restrict__ Wm3, const float* __restrict__ bm3,
                                             float* __restrict__ out, int E) {
    __shared__ float sw1[136 * 64];
    __shared__ float sw2[64 * 32];
    __shared__ float sw3[32];
    __shared__ int sre[64], sce[64];
    __shared__ float sa[64 * 140];
    int t = threadIdx.x;
    for (int i = t; i < 136 * 64; i += 256) sw1[i] = Wm1[i];
    for (int i = t; i < 64 * 32; i += 256) sw2[i] = Wm2[i];
    if (t < 32) sw3[t] = Wm3[t];
    int e0 = blockIdx.x * 64;
    if (t < 64) {
        int e = e0 + t;
        if (e < E) { sre[t] = ei[e]; sce[t] = ei[E + e]; }
        else { sre[t] = 0; sce[t] = 0; }
    }
    __syncthreads();
    // stage er tile: per edge 18 chunks: 8x(8 halfs from h2h[r]) + 8x(8 halfs from h2h[c]) + 2x(float4 ea)
    for (int i = t; i < 64 * 18; i += 256) {
        int el = i / 18, q = i - el * 18;
        float* dst = sa + el * 140;
        if (q < 16) {
            int n = (q < 8) ? sre[el] : sce[el];
            int qq = q & 7;
            float4 hv = *(const float4*)(h2h + (size_t)n * 64 + qq * 8);
            const __half2* hp = (const __half2*)&hv;
            float2 f0 = __half22float2(hp[0]);
            float2 f1 = __half22float2(hp[1]);
            float2 f2 = __half22float2(hp[2]);
            float2 f3 = __half22float2(hp[3]);
            int base = (q < 8) ? qq * 8 : 64 + qq * 8;
            dst[base + 0] = f0.x; dst[base + 1] = f0.y;
            dst[base + 2] = f1.x; dst[base + 3] = f1.y;
            dst[base + 4] = f2.x; dst[base + 5] = f2.y;
            dst[base + 6] = f3.x; dst[base + 7] = f3.y;
        } else {
            int qq = q - 16;
            float4 v = *(const float4*)(ea + (size_t)(e0 + el) * 8 + qq * 4);
            *(float4*)(dst + 128 + qq * 4) = v;
        }
    }
    __syncthreads();
    int tr = t >> 4, tc = t & 15;
    float acc[4][4];
#pragma unroll
    for (int j = 0; j < 4; j++) {
        float bv = bm1[tc * 4 + j];
#pragma unroll
        for (int i = 0; i < 4; i++) acc[i][j] = bv;
    }
    for (int k = 0; k < 136; k++) {
        float4 bv = *(const float4*)(sw1 + k * 64 + tc * 4);
        float a0 = sa[(tr * 4 + 0) * 140 + k];
        float a1 = sa[(tr * 4 + 1) * 140 + k];
        float a2 = sa[(tr * 4 + 2) * 140 + k];
        float a3 = sa[(tr * 4 + 3) * 140 + k];
        acc[0][0] += a0 * bv.x; acc[0][1] += a0 * bv.y; acc[0][2] += a0 * bv.z; acc[0][3] += a0 * bv.w;
        acc[1][0] += a1 * bv.x; acc[1][1] += a1 * bv.y; acc[1][2] += a1 * bv.z; acc[1][3] += a1 * bv.w;
        acc[2][0] += a2 * bv.x; acc[2][1] += a2 * bv.y; acc[2][2] += a2 * bv.z; acc[2][3] += a2 * bv.w;
        acc[3][0] += a3 * bv.x; acc[3][1] += a3 * bv.y; acc[3][2] += a3 * bv.z; acc[3][3] += a3 * bv.w;
    }
    __syncthreads();
#pragma unroll
    for (int i = 0; i < 4; i++) {
        float4 z;
        z.x = gelu_f(acc[i][0]); z.y = gelu_f(acc[i][1]);
        z.z = gelu_f(acc[i][2]); z.w = gelu_f(acc[i][3]);
        *(float4*)(sa + (tr * 4 + i) * 140 + tc * 4) = z;
    }
    __syncthreads();
    float acc2[4][2];
#pragma unroll
    for (int j = 0; j < 2; j++) {
        float bv = bm2[tc * 2 + j];
#pragma unroll
        for (int i = 0; i < 4; i++) acc2[i][j] = bv;
    }
    for (int k = 0; k < 64; k++) {
        float2 bv = *(const float2*)(sw2 + k * 32 + tc * 2);
        float a0 = sa[(tr * 4 + 0) * 140 + k];
        float a1 = sa[(tr * 4 + 1) * 140 + k];
        float a2 = sa[(tr * 4 + 2) * 140 + k];
        float a3 = sa[(tr * 4 + 3) * 140 + k];
        acc2[0][0] += a0 * bv.x; acc2[0][1] += a0 * bv.y;
        acc2[1][0] += a1 * bv.x; acc2[1][1] += a1 * bv.y;
        acc2[2][0] += a2 * bv.x; acc2[2][1] += a2 * bv.y;
        acc2[3][0] += a3 * bv.x; acc2[3][1] += a3 * bv.y;
    }
    __syncthreads();
#pragma unroll
    for (int i = 0; i < 4; i++)
#pragma unroll
        for (int j = 0; j < 2; j++)
            sa[(tr * 4 + i) * 140 + 96 + tc * 2 + j] = gelu_f(acc2[i][j]);
    __syncthreads();
    if (t < 64) {
        float s = bm3[0];
#pragma unroll
        for (int k = 0; k < 32; k++) s += sa[t * 140 + 96 + k] * sw3[k];
        int e = e0 + t;
        if (e < E) out[e] = 1.f / (1.f + expf(-s));
    }
}

extern "C" void kernel_launch(void* const* d_in, const int* in_sizes, int n_in,
                              void* d_out, int out_size, void* d_ws, size_t ws_size,
                              hipStream_t stream) {
    const float* x    = (const float*)d_in[0];
    const int*   ei   = (const int*)d_in[1];
    const float* ea   = (const float*)d_in[2];
    const float* Wl1  = (const float*)d_in[3];
    const float* bl1  = (const float*)d_in[4];
    const float* Wr1  = (const float*)d_in[5];
    const float* br1  = (const float*)d_in[6];
    const float* We1  = (const float*)d_in[7];
    const float* att1 = (const float*)d_in[8];
    const float* bias1= (const float*)d_in[9];
    const float* Wl2  = (const float*)d_in[10];
    const float* bl2  = (const float*)d_in[11];
    const float* Wr2  = (const float*)d_in[12];
    const float* br2  = (const float*)d_in[13];
    const float* We2  = (const float*)d_in[14];
    const float* att2 = (const float*)d_in[15];
    const float* bias2= (const float*)d_in[16];
    const float* bn1g = (const float*)d_in[17];
    const float* bn1b = (const float*)d_in[18];
    const float* bn1m = (const float*)d_in[19];
    const float* bn1v = (const float*)d_in[20];
    const float* bn2g = (const float*)d_in[21];
    const float* bn2b = (const float*)d_in[22];
    const float* bn2m = (const float*)d_in[23];
    const float* bn2v = (const float*)d_in[24];
    const float* Wres = (const float*)d_in[25];
    const float* Wm1  = (const float*)d_in[26];
    const float* bm1  = (const float*)d_in[27];
    const float* Wm2  = (const float*)d_in[28];
    const float* bm2  = (const float*)d_in[29];
    const float* Wm3  = (const float*)d_in[30];
    const float* bm3  = (const float*)d_in[31];
    float* out = (float*)d_out;
    float* ws = (float*)d_ws;

    const int N = NN, E = EE, Etot = ETOT;

    // workspace layout (floats)
    float* ea_sum   = ws;                                     // 16
    int*   counts   = (int*)(ws + 16);                        // N
    int*   off      = (int*)(ws + 16 + (size_t)N);            // N+16
    int*   cursor   = (int*)(ws + 32 + (size_t)2 * N);        // N
    int*   csr_src  = (int*)(ws + 32 + (size_t)3 * N);        // Etot
    int*   csr_eid  = (int*)(ws + 32 + (size_t)3 * N + Etot); // Etot
    size_t base     = 32 + (size_t)3 * N + (size_t)2 * Etot;
    __half* xl1h    = (__half*)(ws + base);                   // 256N halfs = 128N floats
    __half* xl2h    = xl1h;                                   // reuses (xl1h dead after k_fagg1)
    __half* h2h     = (__half*)(ws + base + (size_t)128 * N); // 64N halfs = 32N floats
    float* xr1      = ws + base + (size_t)160 * N;            // 256N floats
    float* h1       = xr1;                                    // in-place (row read before write)
    float* xr2      = xr1 + (size_t)256 * N;                  // 64N floats

    hipMemsetAsync(ea_sum, 0, 16 * sizeof(float), stream);
    hipMemsetAsync(counts, 0, (size_t)N * sizeof(int), stream);

    k_ea_reduce<<<256, 256, 0, stream>>>(ea, ea_sum, E);
    k_count<<<(Etot + 255) / 256, 256, 0, stream>>>(ei, counts, E, N);
    k_scan<<<1, 1024, 0, stream>>>(counts, off, cursor, N);
    k_scatter<<<(Etot + 255) / 256, 256, 0, stream>>>(ei, cursor, csr_src, csr_eid, E, N);
    k_ntrans1<<<(N + 31) / 32, 256, 0, stream>>>(x, Wl1, bl1, Wr1, br1, xl1h, xr1, N);
    k_fagg1<<<(N + 3) / 4, 256, 0, stream>>>(xl1h, xr1, off, csr_src, csr_eid, ea, ea_sum,
                                             We1, att1, bias1, x, Wres,
                                             bn1g, bn1b, bn1m, bn1v, h1, E, N);
    k_xlr2<<<(N + 31) / 32, 256, 0, stream>>>(h1, Wl2, bl2, Wr2, br2, xl2h, xr2, N);
    k_fagg2<<<(N + 3) / 4, 256, 0, stream>>>(xl2h, xr2, off, csr_src, csr_eid, ea, ea_sum,
                                             We2, att2, bias2,
                                             bn2g, bn2b, bn2m, bn2v, h2h, E, N);
    k_mlp<<<(E + 63) / 64, 256, 0, stream>>>(h2h, ei, ea, Wm1, bm1, Wm2, bm2, Wm3, bm3, out, E);
}

// Round 8
// 549.908 us; speedup vs baseline: 2.5575x; 1.1777x over previous
//
#include <hip/hip_runtime.h>
#include <hip/hip_bf16.h>
#include <hip/hip_fp16.h>
#include <math.h>

#define NN 50000
#define EE 400000
#define ETOT (NN + EE)

// ---------- helpers ----------
__device__ __forceinline__ float gelu_f(float x) {
    return 0.5f * x * (1.f + erff(x * 0.7071067811865476f));
}
__device__ __forceinline__ float elu_f(float x) {
    return x > 0.f ? x : expm1f(x);
}
__device__ __forceinline__ float4 half8_lo_hi(uint4 raw, float4* hi) {
    __half2 h0 = *(__half2*)&raw.x, h1 = *(__half2*)&raw.y;
    __half2 h2 = *(__half2*)&raw.z, h3 = *(__half2*)&raw.w;
    float2 f0 = __half22float2(h0), f1 = __half22float2(h1);
    float2 f2 = __half22float2(h2), f3 = __half22float2(h3);
    *hi = make_float4(f2.x, f2.y, f3.x, f3.y);
    return make_float4(f0.x, f0.y, f1.x, f1.y);
}

// ---------- ea mean (sum) ----------
__global__ __launch_bounds__(256) void k_ea_reduce(const float* __restrict__ ea,
                                                   float* __restrict__ ea_sum, int E) {
    float s[8];
#pragma unroll
    for (int i = 0; i < 8; i++) s[i] = 0.f;
    for (int e = blockIdx.x * blockDim.x + threadIdx.x; e < E; e += gridDim.x * blockDim.x) {
        const float4* p = (const float4*)(ea + (size_t)e * 8);
        float4 a = p[0], b = p[1];
        s[0] += a.x; s[1] += a.y; s[2] += a.z; s[3] += a.w;
        s[4] += b.x; s[5] += b.y; s[6] += b.z; s[7] += b.w;
    }
#pragma unroll
    for (int o = 32; o; o >>= 1)
#pragma unroll
        for (int i = 0; i < 8; i++) s[i] += __shfl_xor(s[i], o, 64);
    __shared__ float sh[4][8];
    int lane = threadIdx.x & 63, w = threadIdx.x >> 6;
    if (lane == 0)
#pragma unroll
        for (int i = 0; i < 8; i++) sh[w][i] = s[i];
    __syncthreads();
    if (threadIdx.x < 8) {
        float v = sh[0][threadIdx.x] + sh[1][threadIdx.x] + sh[2][threadIdx.x] + sh[3][threadIdx.x];
        atomicAdd(ea_sum + threadIdx.x, v);
    }
}

// ---------- CSR build: count / scan / scatter ----------
__global__ __launch_bounds__(256) void k_count(const int* __restrict__ ei, int* __restrict__ counts,
                                               int E, int N) {
    int e = blockIdx.x * blockDim.x + threadIdx.x;
    if (e >= E + N) return;
    int d = (e < E) ? ei[E + e] : (e - E);
    atomicAdd(counts + d, 1);
}

__global__ __launch_bounds__(1024) void k_scan(const int* __restrict__ counts, int* __restrict__ off,
                                               int* __restrict__ cursor, int N) {
    __shared__ int buf[1024];
    int t = threadIdx.x;
    int carry = 0;
    if (t == 0) off[0] = 0;
    for (int base = 0; base < N; base += 1024) {
        int i = base + t;
        int v = (i < N) ? counts[i] : 0;
        buf[t] = v;
        __syncthreads();
        for (int o = 1; o < 1024; o <<= 1) {
            int add = (t >= o) ? buf[t - o] : 0;
            __syncthreads();
            buf[t] += add;
            __syncthreads();
        }
        int incl = buf[t] + carry;
        if (i < N) { off[i + 1] = incl; cursor[i] = incl - v; }
        int tot = buf[1023];
        __syncthreads();
        carry += tot;
    }
}

__global__ __launch_bounds__(256) void k_scatter(const int* __restrict__ ei, int* __restrict__ cursor,
                                                 int* __restrict__ csr_src, int* __restrict__ csr_eid,
                                                 int E, int N) {
    int e = blockIdx.x * blockDim.x + threadIdx.x;
    if (e >= E + N) return;
    int s, d;
    if (e < E) { s = ei[e]; d = ei[E + e]; }
    else { s = d = e - E; }
    int pos = atomicAdd(cursor + d, 1);
    csr_src[pos] = s;
    csr_eid[pos] = e;
}

// ---------- node transform 1: xl1(fp16) = x@Wl1+bl1, xr1(fp32) = x@Wr1+br1 ----------
__global__ __launch_bounds__(256) void k_ntrans1(const float* __restrict__ x,
                                                 const float* __restrict__ Wl, const float* __restrict__ bl,
                                                 const float* __restrict__ Wr, const float* __restrict__ br,
                                                 __half* __restrict__ xl1h, float* __restrict__ xr1, int N) {
    __shared__ float swl[16 * 256];
    __shared__ float swr[16 * 256];
    __shared__ float sx[32 * 16];
    int t = threadIdx.x;
#pragma unroll
    for (int k = 0; k < 16; k++) { swl[k * 256 + t] = Wl[k * 256 + t]; swr[k * 256 + t] = Wr[k * 256 + t]; }
    int n0 = blockIdx.x * 32;
    for (int i = t; i < 32 * 16; i += 256) {
        int n = n0 + (i >> 4);
        sx[i] = (n < N) ? x[(size_t)n * 16 + (i & 15)] : 0.f;
    }
    __syncthreads();
    float bL = bl[t], bR = br[t];
    for (int ni = 0; ni < 32; ni++) {
        int n = n0 + ni;
        if (n >= N) break;
        float al = bL, ar = bR;
#pragma unroll
        for (int k = 0; k < 16; k++) {
            float xv = sx[ni * 16 + k];
            al += xv * swl[k * 256 + t];
            ar += xv * swr[k * 256 + t];
        }
        xl1h[(size_t)n * 256 + t] = __float2half(al);
        xr1[(size_t)n * 256 + t] = ar;
    }
}

// ---------- fused conv1: zero-LDS, chunked index/ea broadcast, depth-3 row prefetch ----------
__global__ __launch_bounds__(256) void k_fagg1(const __half* __restrict__ xl1h, const float* __restrict__ xr1,
                                               const int* __restrict__ off, const int* __restrict__ csr_src,
                                               const int* __restrict__ csr_eid,
                                               const float* __restrict__ ea, const float* __restrict__ ea_sum,
                                               const float* __restrict__ We1, const float* __restrict__ att1,
                                               const float* __restrict__ bias1,
                                               const float* __restrict__ x, const float* __restrict__ Wres,
                                               const float* __restrict__ g, const float* __restrict__ bb_,
                                               const float* __restrict__ mm_, const float* __restrict__ vv_,
                                               float* __restrict__ h1,
                                               int E, int N) {
    int t = threadIdx.x;
    int lane = t & 63, w = t >> 6;
    int node = blockIdx.x * 4 + w;
    if (node >= N) return;
    int c4 = lane * 4;
    float4 we[8];
#pragma unroll
    for (int k = 0; k < 8; k++) we[k] = *(const float4*)(We1 + k * 256 + c4);
    float4 xr4 = *(const float4*)(xr1 + (size_t)node * 256 + c4);
    float4 at4 = *(const float4*)(att1 + c4);
    float invE = 1.f / (float)E;
    float4 eam0, eam1;
    eam0.x = ea_sum[0] * invE; eam0.y = ea_sum[1] * invE;
    eam0.z = ea_sum[2] * invE; eam0.w = ea_sum[3] * invE;
    eam1.x = ea_sum[4] * invE; eam1.y = ea_sum[5] * invE;
    eam1.z = ea_sum[6] * invE; eam1.w = ea_sum[7] * invE;

    int beg = off[node], end = off[node + 1];
    float m = -1e30f, sumw = 0.f;
    float4 acc = make_float4(0.f, 0.f, 0.f, 0.f);

    int cb = beg;
    while (cb < end) {
        int cnt = end - cb; if (cnt > 64) cnt = 64;
        int sl = 0;
        float4 ba = eam0, bb4 = eam1;
        if (lane < cnt) {
            sl = csr_src[cb + lane];
            int el = csr_eid[cb + lane];
            if (el < E) {
                ba  = *(const float4*)(ea + (size_t)el * 8);
                bb4 = *(const float4*)(ea + (size_t)el * 8 + 4);
            }
        }
        float2 r0 = make_float2(0.f, 0.f), r1 = r0, r2 = r0;
        {
            int s0 = __shfl(sl, 0, 64);
            r0 = *(const float2*)(xl1h + (size_t)s0 * 256 + c4);
            if (cnt > 1) { int s1 = __shfl(sl, 1, 64); r1 = *(const float2*)(xl1h + (size_t)s1 * 256 + c4); }
            if (cnt > 2) { int s2 = __shfl(sl, 2, 64); r2 = *(const float2*)(xl1h + (size_t)s2 * 256 + c4); }
        }
        for (int j = 0; j < cnt; j++) {
            float2 cur = r0;
            r0 = r1; r1 = r2;
            if (j + 3 < cnt) {
                int s3 = __shfl(sl, j + 3, 64);
                r2 = *(const float2*)(xl1h + (size_t)s3 * 256 + c4);
            }
            float eav[8];
            eav[0] = __shfl(ba.x, j, 64);  eav[1] = __shfl(ba.y, j, 64);
            eav[2] = __shfl(ba.z, j, 64);  eav[3] = __shfl(ba.w, j, 64);
            eav[4] = __shfl(bb4.x, j, 64); eav[5] = __shfl(bb4.y, j, 64);
            eav[6] = __shfl(bb4.z, j, 64); eav[7] = __shfl(bb4.w, j, 64);
            const __half2* hp = (const __half2*)&cur;
            float2 lo = __half22float2(hp[0]);
            float2 hi = __half22float2(hp[1]);
            float4 xs = make_float4(lo.x, lo.y, hi.x, hi.y);
            float4 ee = make_float4(0.f, 0.f, 0.f, 0.f);
#pragma unroll
            for (int k = 0; k < 8; k++) {
                ee.x += eav[k] * we[k].x; ee.y += eav[k] * we[k].y;
                ee.z += eav[k] * we[k].z; ee.w += eav[k] * we[k].w;
            }
            float4 v;
            v.x = xs.x + xr4.x + ee.x; v.y = xs.y + xr4.y + ee.y;
            v.z = xs.z + xr4.z + ee.z; v.w = xs.w + xr4.w + ee.w;
            v.x = v.x > 0.f ? v.x : 0.2f * v.x;
            v.y = v.y > 0.f ? v.y : 0.2f * v.y;
            v.z = v.z > 0.f ? v.z : 0.2f * v.z;
            v.w = v.w > 0.f ? v.w : 0.2f * v.w;
            float p = v.x * at4.x + v.y * at4.y + v.z * at4.z + v.w * at4.w;
            p += __shfl_xor(p, 1, 64);
            p += __shfl_xor(p, 2, 64);
            p += __shfl_xor(p, 4, 64);
            p += __shfl_xor(p, 8, 64);
            float mn = fmaxf(m, p);
            float sc = expf(m - mn);
            float wgt = expf(p - mn);
            acc.x = acc.x * sc + wgt * xs.x;
            acc.y = acc.y * sc + wgt * xs.y;
            acc.z = acc.z * sc + wgt * xs.z;
            acc.w = acc.w * sc + wgt * xs.w;
            sumw = sumw * sc + wgt;
            m = mn;
        }
        cb += cnt;
    }
    float inv = 1.f / (sumw + 1e-16f);
    float4 r = make_float4(0.f, 0.f, 0.f, 0.f);
#pragma unroll
    for (int q = 0; q < 4; q++) {
        float4 xq = *(const float4*)(x + (size_t)node * 16 + q * 4);
        float xa[4] = { xq.x, xq.y, xq.z, xq.w };
#pragma unroll
        for (int kk = 0; kk < 4; kk++) {
            float4 wv = *(const float4*)(Wres + (size_t)(q * 4 + kk) * 256 + c4);
            r.x += xa[kk] * wv.x; r.y += xa[kk] * wv.y;
            r.z += xa[kk] * wv.z; r.w += xa[kk] * wv.w;
        }
    }
    float4 bi = *(const float4*)(bias1 + c4);
    float4 g4 = *(const float4*)(g + c4);
    float4 b4 = *(const float4*)(bb_ + c4);
    float4 m4 = *(const float4*)(mm_ + c4);
    float4 v4 = *(const float4*)(vv_ + c4);
    float4 o;
    o.x = acc.x * inv + bi.x; o.y = acc.y * inv + bi.y;
    o.z = acc.z * inv + bi.z; o.w = acc.w * inv + bi.w;
    o.x = (o.x - m4.x) * rsqrtf(v4.x + 1e-5f) * g4.x + b4.x + r.x;
    o.y = (o.y - m4.y) * rsqrtf(v4.y + 1e-5f) * g4.y + b4.y + r.y;
    o.z = (o.z - m4.z) * rsqrtf(v4.z + 1e-5f) * g4.z + b4.z + r.z;
    o.w = (o.w - m4.w) * rsqrtf(v4.w + 1e-5f) * g4.w + b4.w + r.w;
    o.x = elu_f(o.x); o.y = elu_f(o.y); o.z = elu_f(o.z); o.w = elu_f(o.w);
    *(float4*)(h1 + (size_t)node * 256 + c4) = o;
}

// ---------- xl2(fp16) = h1@Wl2+bl2, xr2(fp32) = h1@Wr2+br2 ----------
__global__ __launch_bounds__(256) void k_xlr2(const float* __restrict__ h1,
                                              const float* __restrict__ Wl2, const float* __restrict__ bl2,
                                              const float* __restrict__ Wr2, const float* __restrict__ br2,
                                              __half* __restrict__ xl2h, float* __restrict__ xr2, int N) {
    __shared__ float sh[32][32];    // [kk][node]
    __shared__ float sw[32][128];   // [kk][col]
    int t = threadIdx.x;
    int tr = t >> 5, tc = t & 31;
    int n0 = blockIdx.x * 32;
    float acc[4][4];
#pragma unroll
    for (int i = 0; i < 4; i++)
#pragma unroll
        for (int j = 0; j < 4; j++) acc[i][j] = 0.f;
    for (int k0 = 0; k0 < 256; k0 += 32) {
        {
            int n = t >> 3, kk0 = (t & 7) * 4;
            int gn = n0 + n;
            float4 hv = make_float4(0.f, 0.f, 0.f, 0.f);
            if (gn < N) hv = *(const float4*)(h1 + (size_t)gn * 256 + k0 + kk0);
            sh[kk0 + 0][n] = hv.x; sh[kk0 + 1][n] = hv.y; sh[kk0 + 2][n] = hv.z; sh[kk0 + 3][n] = hv.w;
        }
        for (int i = t; i < 32 * 128; i += 256) {
            int kk = i >> 7, c = i & 127;
            sw[kk][c] = (c < 64) ? Wl2[(size_t)(k0 + kk) * 64 + c] : Wr2[(size_t)(k0 + kk) * 64 + (c - 64)];
        }
        __syncthreads();
#pragma unroll
        for (int kk = 0; kk < 32; kk++) {
            float4 hv = *(const float4*)&sh[kk][tr * 4];
            float4 wv = *(const float4*)&sw[kk][tc * 4];
            float hh[4] = { hv.x, hv.y, hv.z, hv.w };
            float wwv[4] = { wv.x, wv.y, wv.z, wv.w };
#pragma unroll
            for (int i = 0; i < 4; i++)
#pragma unroll
                for (int j = 0; j < 4; j++) acc[i][j] += hh[i] * wwv[j];
        }
        __syncthreads();
    }
#pragma unroll
    for (int i = 0; i < 4; i++) {
        int gn = n0 + tr * 4 + i;
        if (gn >= N) continue;
#pragma unroll
        for (int j = 0; j < 4; j++) {
            int c = tc * 4 + j;
            float vv = acc[i][j];
            if (c < 64) xl2h[(size_t)gn * 64 + c] = __float2half(vv + bl2[c]);
            else        xr2[(size_t)gn * 64 + (c - 64)] = vv + br2[c - 64];
        }
    }
}

// ---------- fused conv2: zero-LDS, chunked broadcast, depth-3 prefetch ----------
__global__ __launch_bounds__(256) void k_fagg2(const __half* __restrict__ xl2h, const float* __restrict__ xr2,
                                               const int* __restrict__ off, const int* __restrict__ csr_src,
                                               const int* __restrict__ csr_eid,
                                               const float* __restrict__ ea, const float* __restrict__ ea_sum,
                                               const float* __restrict__ We2, const float* __restrict__ att2,
                                               const float* __restrict__ bias2,
                                               const float* __restrict__ g, const float* __restrict__ bb_,
                                               const float* __restrict__ mm_, const float* __restrict__ vv_,
                                               __half* __restrict__ h2h,
                                               int E, int N) {
    int t = threadIdx.x;
    int lane = t & 63, w = t >> 6;
    int node = blockIdx.x * 4 + w;
    if (node >= N) return;
    float we[8];
#pragma unroll
    for (int k = 0; k < 8; k++) we[k] = We2[k * 64 + lane];
    float xr = xr2[(size_t)node * 64 + lane];
    float at = att2[lane];
    float invE = 1.f / (float)E;
    float4 eam0, eam1;
    eam0.x = ea_sum[0] * invE; eam0.y = ea_sum[1] * invE;
    eam0.z = ea_sum[2] * invE; eam0.w = ea_sum[3] * invE;
    eam1.x = ea_sum[4] * invE; eam1.y = ea_sum[5] * invE;
    eam1.z = ea_sum[6] * invE; eam1.w = ea_sum[7] * invE;

    int beg = off[node], end = off[node + 1];
    float m = -1e30f, sumw = 0.f, acc = 0.f;

    int cb = beg;
    while (cb < end) {
        int cnt = end - cb; if (cnt > 64) cnt = 64;
        int sl = 0;
        float4 ba = eam0, bb4 = eam1;
        if (lane < cnt) {
            sl = csr_src[cb + lane];
            int el = csr_eid[cb + lane];
            if (el < E) {
                ba  = *(const float4*)(ea + (size_t)el * 8);
                bb4 = *(const float4*)(ea + (size_t)el * 8 + 4);
            }
        }
        float r0 = 0.f, r1 = 0.f, r2 = 0.f;
        {
            int s0 = __shfl(sl, 0, 64);
            r0 = __half2float(xl2h[(size_t)s0 * 64 + lane]);
            if (cnt > 1) { int s1 = __shfl(sl, 1, 64); r1 = __half2float(xl2h[(size_t)s1 * 64 + lane]); }
            if (cnt > 2) { int s2 = __shfl(sl, 2, 64); r2 = __half2float(xl2h[(size_t)s2 * 64 + lane]); }
        }
        for (int j = 0; j < cnt; j++) {
            float xs = r0;
            r0 = r1; r1 = r2;
            if (j + 3 < cnt) {
                int s3 = __shfl(sl, j + 3, 64);
                r2 = __half2float(xl2h[(size_t)s3 * 64 + lane]);
            }
            float eav[8];
            eav[0] = __shfl(ba.x, j, 64);  eav[1] = __shfl(ba.y, j, 64);
            eav[2] = __shfl(ba.z, j, 64);  eav[3] = __shfl(ba.w, j, 64);
            eav[4] = __shfl(bb4.x, j, 64); eav[5] = __shfl(bb4.y, j, 64);
            eav[6] = __shfl(bb4.z, j, 64); eav[7] = __shfl(bb4.w, j, 64);
            float v = xs + xr;
#pragma unroll
            for (int k = 0; k < 8; k++) v += eav[k] * we[k];
            v = v > 0.f ? v : 0.2f * v;
            float p = v * at;
#pragma unroll
            for (int o = 32; o; o >>= 1) p += __shfl_xor(p, o, 64);
            float mn = fmaxf(m, p);
            float sc = expf(m - mn);
            float wgt = expf(p - mn);
            acc = acc * sc + wgt * xs;
            sumw = sumw * sc + wgt;
            m = mn;
        }
        cb += cnt;
    }
    float val = acc / (sumw + 1e-16f) + bias2[lane];
    val = (val - mm_[lane]) * rsqrtf(vv_[lane] + 1e-5f) * g[lane] + bb_[lane];
    h2h[(size_t)node * 64 + lane] = __float2half(elu_f(val));
}

// ---------- u = h2@Wm1[0:64], v = h2@Wm1[64:128]  (fp16 out, no bias) ----------
__global__ __launch_bounds__(256) void k_uv(const __half* __restrict__ h2h, const float* __restrict__ Wm1,
                                            __half* __restrict__ uh, __half* __restrict__ vh, int N) {
    __shared__ float sh[32][32];    // [kk][node]
    __shared__ float sw[32][128];   // [kk][col]  (u cols 0..63, v cols 64..127)
    int t = threadIdx.x;
    int tr = t >> 5, tc = t & 31;
    int n0 = blockIdx.x * 32;
    float acc[4][4];
#pragma unroll
    for (int i = 0; i < 4; i++)
#pragma unroll
        for (int j = 0; j < 4; j++) acc[i][j] = 0.f;
    for (int k0 = 0; k0 < 64; k0 += 32) {
        {
            int n = t >> 3, kk0 = (t & 7) * 4;
            int gn = n0 + n;
            float4 hv = make_float4(0.f, 0.f, 0.f, 0.f);
            if (gn < N) {
                uint2 raw = *(const uint2*)(h2h + (size_t)gn * 64 + k0 + kk0);
                __half2 a = *(__half2*)&raw.x, b = *(__half2*)&raw.y;
                float2 fa = __half22float2(a), fb = __half22float2(b);
                hv = make_float4(fa.x, fa.y, fb.x, fb.y);
            }
            sh[kk0 + 0][n] = hv.x; sh[kk0 + 1][n] = hv.y; sh[kk0 + 2][n] = hv.z; sh[kk0 + 3][n] = hv.w;
        }
        for (int i = t; i < 32 * 128; i += 256) {
            int kk = i >> 7, c = i & 127;
            sw[kk][c] = (c < 64) ? Wm1[(size_t)(k0 + kk) * 64 + c]
                                 : Wm1[(size_t)(64 + k0 + kk) * 64 + (c - 64)];
        }
        __syncthreads();
#pragma unroll
        for (int kk = 0; kk < 32; kk++) {
            float4 hv = *(const float4*)&sh[kk][tr * 4];
            float4 wv = *(const float4*)&sw[kk][tc * 4];
            float hh[4] = { hv.x, hv.y, hv.z, hv.w };
            float wwv[4] = { wv.x, wv.y, wv.z, wv.w };
#pragma unroll
            for (int i = 0; i < 4; i++)
#pragma unroll
                for (int j = 0; j < 4; j++) acc[i][j] += hh[i] * wwv[j];
        }
        __syncthreads();
    }
#pragma unroll
    for (int i = 0; i < 4; i++) {
        int gn = n0 + tr * 4 + i;
        if (gn >= N) continue;
#pragma unroll
        for (int j = 0; j < 4; j++) {
            int c = tc * 4 + j;
            if (c < 64) uh[(size_t)gn * 64 + c] = __float2half(acc[i][j]);
            else        vh[(size_t)gn * 64 + (c - 64)] = __float2half(acc[i][j]);
        }
    }
}

// ---------- weA[e] = ea[e]@Wm1[128:136] + bm1  (fp16 out, coalesced) ----------
__global__ __launch_bounds__(256) void k_wea(const float* __restrict__ ea, const float* __restrict__ Wm1,
                                             const float* __restrict__ bm1,
                                             __half* __restrict__ weAh, int E) {
    __shared__ float sW[8 * 64];
    int t = threadIdx.x;
    for (int i = t; i < 512; i += 256) sW[i] = Wm1[128 * 64 + i];   // FIX: full 512-float load with 256 threads
    __syncthreads();
    int i = blockIdx.x * 256 + t;
    if (i >= E * 8) return;
    int e = i >> 3, q = i & 7;
    float4 a0 = *(const float4*)(ea + (size_t)e * 8);
    float4 a1 = *(const float4*)(ea + (size_t)e * 8 + 4);
    float av[8] = { a0.x, a0.y, a0.z, a0.w, a1.x, a1.y, a1.z, a1.w };
    float o[8];
#pragma unroll
    for (int j = 0; j < 8; j++) o[j] = bm1[q * 8 + j];
#pragma unroll
    for (int k = 0; k < 8; k++) {
        float a = av[k];
#pragma unroll
        for (int j = 0; j < 8; j++) o[j] += a * sW[k * 64 + q * 8 + j];
    }
    __half2 h[4];
#pragma unroll
    for (int j = 0; j < 4; j++) h[j] = __floats2half2_rn(o[2 * j], o[2 * j + 1]);
    *(uint4*)(weAh + (size_t)e * 64 + q * 8) = *(uint4*)h;
}

// ---------- edge MLP head v2: z1 = gelu(u[r]+v[c]+weA[e]); layer2+3 fused ----------
__global__ __launch_bounds__(256) void k_mlp2(const __half* __restrict__ uh, const __half* __restrict__ vh,
                                              const __half* __restrict__ weAh, const int* __restrict__ ei,
                                              const float* __restrict__ Wm2, const float* __restrict__ bm2,
                                              const float* __restrict__ Wm3, const float* __restrict__ bm3,
                                              float* __restrict__ out, int E) {
    __shared__ float sw2[64 * 32];
    __shared__ int sre[64], sce[64];
    __shared__ float z1[64 * 68];
    int t = threadIdx.x;
    for (int i = t; i < 64 * 32; i += 256) sw2[i] = Wm2[i];
    int e0 = blockIdx.x * 64;
    if (t < 64) {
        int e = e0 + t;
        if (e < E) { sre[t] = ei[e]; sce[t] = ei[E + e]; }
        else { sre[t] = 0; sce[t] = 0; }
    }
    __syncthreads();
    // stage z1 = gelu(u[r] + v[c] + weA[e]) : 64 edges x 8 q-chunks of 8 cols
    for (int i = t; i < 512; i += 256) {
        int el = i >> 3, q = i & 7;
        int r = sre[el], c = sce[el];
        uint4 ru = *(const uint4*)(uh + (size_t)r * 64 + q * 8);
        uint4 rv = *(const uint4*)(vh + (size_t)c * 64 + q * 8);
        uint4 rw = *(const uint4*)(weAh + (size_t)(e0 + el) * 64 + q * 8);
        float4 uhi, vhi, whi;
        float4 ulo = half8_lo_hi(ru, &uhi);
        float4 vlo = half8_lo_hi(rv, &vhi);
        float4 wlo = half8_lo_hi(rw, &whi);
        float4 zlo, zhi;
        zlo.x = gelu_f(ulo.x + vlo.x + wlo.x);
        zlo.y = gelu_f(ulo.y + vlo.y + wlo.y);
        zlo.z = gelu_f(ulo.z + vlo.z + wlo.z);
        zlo.w = gelu_f(ulo.w + vlo.w + wlo.w);
        zhi.x = gelu_f(uhi.x + vhi.x + whi.x);
        zhi.y = gelu_f(uhi.y + vhi.y + whi.y);
        zhi.z = gelu_f(uhi.z + vhi.z + whi.z);
        zhi.w = gelu_f(uhi.w + vhi.w + whi.w);
        *(float4*)(z1 + el * 68 + q * 8)     = zlo;
        *(float4*)(z1 + el * 68 + q * 8 + 4) = zhi;
    }
    __syncthreads();
    // layer 2: per thread 2 edges x 4 cols; layer 3 via 8-lane shuffle reduce
    int tr = t >> 3;      // 0..31 -> edges tr*2, tr*2+1
    int tc = t & 7;       // cols tc*4 .. tc*4+3
    float b2[4], w3[4];
#pragma unroll
    for (int j = 0; j < 4; j++) { b2[j] = bm2[tc * 4 + j]; w3[j] = Wm3[tc * 4 + j]; }
    float b3 = bm3[0];
    float acc0[4], acc1[4];
#pragma unroll
    for (int j = 0; j < 4; j++) { acc0[j] = 0.f; acc1[j] = 0.f; }
    const float* z0p = z1 + (tr * 2 + 0) * 68;
    const float* z1p = z1 + (tr * 2 + 1) * 68;
#pragma unroll 8
    for (int k = 0; k < 64; k++) {
        float4 wv = *(const float4*)(sw2 + k * 32 + tc * 4);
        float a0 = z0p[k];
        float a1 = z1p[k];
        acc0[0] += a0 * wv.x; acc0[1] += a0 * wv.y; acc0[2] += a0 * wv.z; acc0[3] += a0 * wv.w;
        acc1[0] += a1 * wv.x; acc1[1] += a1 * wv.y; acc1[2] += a1 * wv.z; acc1[3] += a1 * wv.w;
    }
    float p0 = 0.f, p1 = 0.f;
#pragma unroll
    for (int j = 0; j < 4; j++) {
        p0 += gelu_f(acc0[j] + b2[j]) * w3[j];
        p1 += gelu_f(acc1[j] + b2[j]) * w3[j];
    }
    p0 += __shfl_xor(p0, 1, 64); p0 += __shfl_xor(p0, 2, 64); p0 += __shfl_xor(p0, 4, 64);
    p1 += __shfl_xor(p1, 1, 64); p1 += __shfl_xor(p1, 2, 64); p1 += __shfl_xor(p1, 4, 64);
    if (tc == 0) {
        int e = e0 + tr * 2;
        if (e < E)     out[e]     = 1.f / (1.f + expf(-(p0 + b3)));
        if (e + 1 < E) out[e + 1] = 1.f / (1.f + expf(-(p1 + b3)));
    }
}

extern "C" void kernel_launch(void* const* d_in, const int* in_sizes, int n_in,
                              void* d_out, int out_size, void* d_ws, size_t ws_size,
                              hipStream_t stream) {
    const float* x    = (const float*)d_in[0];
    const int*   ei   = (const int*)d_in[1];
    const float* ea   = (const float*)d_in[2];
    const float* Wl1  = (const float*)d_in[3];
    const float* bl1  = (const float*)d_in[4];
    const float* Wr1  = (const float*)d_in[5];
    const float* br1  = (const float*)d_in[6];
    const float* We1  = (const float*)d_in[7];
    const float* att1 = (const float*)d_in[8];
    const float* bias1= (const float*)d_in[9];
    const float* Wl2  = (const float*)d_in[10];
    const float* bl2  = (const float*)d_in[11];
    const float* Wr2  = (const float*)d_in[12];
    const float* br2  = (const float*)d_in[13];
    const float* We2  = (const float*)d_in[14];
    const float* att2 = (const float*)d_in[15];
    const float* bias2= (const float*)d_in[16];
    const float* bn1g = (const float*)d_in[17];
    const float* bn1b = (const float*)d_in[18];
    const float* bn1m = (const float*)d_in[19];
    const float* bn1v = (const float*)d_in[20];
    const float* bn2g = (const float*)d_in[21];
    const float* bn2b = (const float*)d_in[22];
    const float* bn2m = (const float*)d_in[23];
    const float* bn2v = (const float*)d_in[24];
    const float* Wres = (const float*)d_in[25];
    const float* Wm1  = (const float*)d_in[26];
    const float* bm1  = (const float*)d_in[27];
    const float* Wm2  = (const float*)d_in[28];
    const float* bm2  = (const float*)d_in[29];
    const float* Wm3  = (const float*)d_in[30];
    const float* bm3  = (const float*)d_in[31];
    float* out = (float*)d_out;
    float* ws = (float*)d_ws;

    const int N = NN, E = EE, Etot = ETOT;

    // workspace layout (floats)
    float* ea_sum   = ws;                                     // 16
    int*   counts   = (int*)(ws + 16);                        // N
    int*   off      = (int*)(ws + 16 + (size_t)N);            // N+16
    int*   cursor   = (int*)(ws + 32 + (size_t)2 * N);        // N
    int*   csr_src  = (int*)(ws + 32 + (size_t)3 * N);        // Etot
    int*   csr_eid  = (int*)(ws + 32 + (size_t)3 * N + Etot); // Etot
    size_t base     = 32 + (size_t)3 * N + (size_t)2 * Etot;
    __half* xl1h    = (__half*)(ws + base);                   // 256N halfs = 128N floats
    __half* xl2h    = xl1h;                                   // reuses (xl1h dead after k_fagg1)
    __half* h2h     = (__half*)(ws + base + (size_t)128 * N); // 64N halfs = 32N floats
    float* xr1      = ws + base + (size_t)160 * N;            // 256N floats
    float* h1       = xr1;                                    // in-place (row read before write)
    __half* weAh    = (__half*)xr1;                           // E*64 halfs = 51.2MB, fits xr1's 256N floats
                                                              // (h1 dead after k_xlr2; k_wea runs after k_fagg2)
    float* xr2      = xr1 + (size_t)256 * N;                  // 64N floats
    __half* uh      = (__half*)xr2;                           // 64N halfs
    __half* vh      = uh + (size_t)64 * N;                    // 64N halfs (xr2 dead after k_fagg2)

    hipMemsetAsync(ea_sum, 0, 16 * sizeof(float), stream);
    hipMemsetAsync(counts, 0, (size_t)N * sizeof(int), stream);

    k_ea_reduce<<<256, 256, 0, stream>>>(ea, ea_sum, E);
    k_count<<<(Etot + 255) / 256, 256, 0, stream>>>(ei, counts, E, N);
    k_scan<<<1, 1024, 0, stream>>>(counts, off, cursor, N);
    k_scatter<<<(Etot + 255) / 256, 256, 0, stream>>>(ei, cursor, csr_src, csr_eid, E, N);
    k_ntrans1<<<(N + 31) / 32, 256, 0, stream>>>(x, Wl1, bl1, Wr1, br1, xl1h, xr1, N);
    k_fagg1<<<(N + 3) / 4, 256, 0, stream>>>(xl1h, xr1, off, csr_src, csr_eid, ea, ea_sum,
                                             We1, att1, bias1, x, Wres,
                                             bn1g, bn1b, bn1m, bn1v, h1, E, N);
    k_xlr2<<<(N + 31) / 32, 256, 0, stream>>>(h1, Wl2, bl2, Wr2, br2, xl2h, xr2, N);
    k_fagg2<<<(N + 3) / 4, 256, 0, stream>>>(xl2h, xr2, off, csr_src, csr_eid, ea, ea_sum,
                                             We2, att2, bias2,
                                             bn2g, bn2b, bn2m, bn2v, h2h, E, N);
    // h1 (xr1 region) now dead -> weAh overlay; xr2 now dead -> uh/vh overlay
    k_wea<<<(E * 8 + 255) / 256, 256, 0, stream>>>(ea, Wm1, bm1, weAh, E);
    k_uv<<<(N + 31) / 32, 256, 0, stream>>>(h2h, Wm1, uh, vh, N);
    k_mlp2<<<(E + 63) / 64, 256, 0, stream>>>(uh, vh, weAh, ei, Wm2, bm2, Wm3, bm3, out, E);
}